// Round 15
// baseline (1100.890 us; speedup 1.0000x reference)
//
#include <hip/hip_runtime.h>
#include <hip/hip_bf16.h>
#include <hip/hip_fp8.h>

#define CEPS 1e-8f

typedef __attribute__((ext_vector_type(8))) __bf16 bf16x8;
typedef __attribute__((ext_vector_type(4))) float f32x4;
typedef __attribute__((ext_vector_type(16))) float f32x16;
typedef __attribute__((ext_vector_type(8))) int i32x8;

__device__ __forceinline__ void gload_lds16(const void* g, void* l) {
  __builtin_amdgcn_global_load_lds((const __attribute__((address_space(1))) unsigned int*)g,
                                   (__attribute__((address_space(3))) unsigned int*)l, 16, 0, 0);
}

__device__ __forceinline__ float gelu_f(float v) {
  return 0.5f * v * (1.0f + erff(v * 0.70710678118654752f));
}

__device__ __forceinline__ unsigned char f32_to_e4m3(float v) {
  __hip_fp8_e4m3 t(v);
  return (unsigned char)t.__x;
}

// ================= device bodies =================

// ---- magnitude + concat(bf16) + row norm ----
__device__ __forceinline__ void dev_mag(double* red, const float* __restrict__ re,
                                        const float* __restrict__ im, float* __restrict__ mag,
                                        __hip_bfloat16* __restrict__ xcat, float* __restrict__ xn,
                                        int row) {
  const float* r = re + (size_t)row * 512;
  const float* q = im + (size_t)row * 512;
  double ss = 0.0;
  for (int d = threadIdx.x; d < 512; d += 256) {
    float a = r[d], b = q[d];
    float s = __fadd_rn(__fmul_rn(a, a), __fmul_rn(b, b));  // match np rounding
    float m = __fsqrt_rn(s);
    mag[(size_t)row * 512 + d] = m;
    xcat[(size_t)row * 1024 + d] = __float2bfloat16(a);
    xcat[(size_t)row * 1024 + 512 + d] = __float2bfloat16(b);
    ss += (double)m * (double)m;
  }
  for (int off = 32; off; off >>= 1) ss += __shfl_xor(ss, off);
  int lane = threadIdx.x & 63, wave = threadIdx.x >> 6;
  if (lane == 0) red[wave] = ss;
  __syncthreads();
  if (threadIdx.x == 0) {
    double tot = red[0] + red[1] + red[2] + red[3];
    float n = (float)sqrt(tot);
    xn[row] = fmaxf(n, CEPS);
  }
}

// ---- concept magnitude (transposed) + norms ----
__device__ __forceinline__ void dev_cmag(double* red, const float* __restrict__ cre,
                                         const float* __restrict__ cim, float* __restrict__ cmagT,
                                         float* __restrict__ yn, int c) {
  const float* r = cre + (size_t)c * 512;
  const float* q = cim + (size_t)c * 512;
  double ss = 0.0;
  for (int d = threadIdx.x; d < 512; d += 256) {
    float a = r[d], b = q[d];
    float s = __fadd_rn(__fmul_rn(a, a), __fmul_rn(b, b));
    float m = __fsqrt_rn(s);
    cmagT[(size_t)d * 1000 + c] = m;
    ss += (double)m * (double)m;
  }
  for (int off = 32; off; off >>= 1) ss += __shfl_xor(ss, off);
  int lane = threadIdx.x & 63, wave = threadIdx.x >> 6;
  if (lane == 0) red[wave] = ss;
  __syncthreads();
  if (threadIdx.x == 0) {
    double tot = red[0] + red[1] + red[2] + red[3];
    float n = (float)sqrt(tot);
    yn[c] = fmaxf(n, CEPS);
  }
}

// ---- transpose: W[K,N] f32 -> Wt[n][k] (OUTT 0=bf16, 1=fp8; zero-pad n>=N) ----
template <int OUTT>
__device__ __forceinline__ void dev_tr(float (*t32)[65], const float* __restrict__ W,
                                       void* __restrict__ Wt, int K, int N, int bx, int by) {
  int n0 = bx * 64, k0 = by * 64;
  int tid = threadIdx.x;
  {
    int nc = tid & 15, kr4 = tid >> 4;
#pragma unroll
    for (int p = 0; p < 4; ++p) {
      int kr = p * 16 + kr4;
      int n = n0 + nc * 4;
      float4 v = make_float4(0.f, 0.f, 0.f, 0.f);
      if (n < N) v = *(const float4*)(W + (size_t)(k0 + kr) * N + n);
      t32[kr][nc * 4 + 0] = v.x; t32[kr][nc * 4 + 1] = v.y;
      t32[kr][nc * 4 + 2] = v.z; t32[kr][nc * 4 + 3] = v.w;
    }
  }
  __syncthreads();
  {
    int kc = tid & 15, nr4 = tid >> 4;
#pragma unroll
    for (int p = 0; p < 4; ++p) {
      int nr = p * 16 + nr4;
      if (OUTT == 0) {
        ushort4 o;
        __hip_bfloat16 h0 = __float2bfloat16(t32[kc * 4 + 0][nr]);
        __hip_bfloat16 h1 = __float2bfloat16(t32[kc * 4 + 1][nr]);
        __hip_bfloat16 h2 = __float2bfloat16(t32[kc * 4 + 2][nr]);
        __hip_bfloat16 h3 = __float2bfloat16(t32[kc * 4 + 3][nr]);
        o.x = *(unsigned short*)&h0; o.y = *(unsigned short*)&h1;
        o.z = *(unsigned short*)&h2; o.w = *(unsigned short*)&h3;
        *(ushort4*)((unsigned short*)Wt + (size_t)(n0 + nr) * K + k0 + kc * 4) = o;
      } else {
        unsigned int o = (unsigned int)f32_to_e4m3(t32[kc * 4 + 0][nr]) |
                         ((unsigned int)f32_to_e4m3(t32[kc * 4 + 1][nr]) << 8) |
                         ((unsigned int)f32_to_e4m3(t32[kc * 4 + 2][nr]) << 16) |
                         ((unsigned int)f32_to_e4m3(t32[kc * 4 + 3][nr]) << 24);
        *(unsigned int*)((unsigned char*)Wt + (size_t)(n0 + nr) * K + k0 + kc * 4) = o;
      }
    }
  }
}

// ---- 128x128 bf16 MFMA GEMM with gelu epilogue (MLP layers) ----
template <int OUTT>
__device__ __forceinline__ void dev_mlp(short* Al, short* Bl, const __hip_bfloat16* __restrict__ A,
                                        const __hip_bfloat16* __restrict__ Bt, void* __restrict__ C,
                                        int M, int N, int K, int ldc, const float* __restrict__ bias,
                                        int bx, int by) {
  const int tid = threadIdx.x, lane = tid & 63, wave = tid >> 6;
  const int m0 = by * 128, n0 = bx * 128;
  const int wr = wave >> 1, wc = wave & 1;
  f32x4 acc[4][4];
  f32x4 zero4 = {0.f, 0.f, 0.f, 0.f};
#pragma unroll
  for (int i = 0; i < 4; ++i)
#pragma unroll
    for (int j = 0; j < 4; ++j) acc[i][j] = zero4;

  const short* Ag = (const short*)A;
  const short* Bg = (const short*)Bt;
  for (int k0 = 0; k0 < K; k0 += 32) {
#pragma unroll
    for (int s = 0; s < 2; ++s) {
      int seg = wave + s * 4;
      int elem = seg * 512 + lane * 8;
      int row = elem >> 5, kk = elem & 31;
      gload_lds16(Ag + (size_t)(m0 + row) * K + k0 + kk, Al + elem);
      gload_lds16(Bg + (size_t)(n0 + row) * K + k0 + kk, Bl + elem);
    }
    __syncthreads();
    bf16x8 af[4], bfr[4];
    const int fr = lane & 15, fk = (lane >> 4) << 3;
#pragma unroll
    for (int i = 0; i < 4; ++i)
      af[i] = *(const bf16x8*)(Al + (wr * 64 + i * 16 + fr) * 32 + fk);
#pragma unroll
    for (int j = 0; j < 4; ++j)
      bfr[j] = *(const bf16x8*)(Bl + (wc * 64 + j * 16 + fr) * 32 + fk);
#pragma unroll
    for (int i = 0; i < 4; ++i)
#pragma unroll
      for (int j = 0; j < 4; ++j)
        acc[i][j] = __builtin_amdgcn_mfma_f32_16x16x32_bf16(af[i], bfr[j], acc[i][j], 0, 0, 0);
    __syncthreads();
  }
  const int fr = lane & 15, fq = lane >> 4;
#pragma unroll
  for (int j = 0; j < 4; ++j) {
    int col = n0 + wc * 64 + j * 16 + fr;
    if (col >= N) continue;
    float bv = bias[col];
#pragma unroll
    for (int i = 0; i < 4; ++i) {
      int rbase = m0 + wr * 64 + i * 16 + fq * 4;
#pragma unroll
      for (int r = 0; r < 4; ++r) {
        float v = gelu_f(acc[i][j][r] + bv);
        if (OUTT == 0)
          ((__hip_bfloat16*)C)[(size_t)(rbase + r) * ldc + col] = __float2bfloat16(v);
        else
          ((unsigned char*)C)[(size_t)(rbase + r) * ldc + col] = f32_to_e4m3(v);
      }
    }
  }
}

// ---- dots GEMM, f64 acc; LDS padded [16][65] (conflict-free); FMA order = rounds 7-14 ----
__device__ __forceinline__ void dev_dots(double (*As)[65], double (*Bs)[65],
                                         const float* __restrict__ A, const float* __restrict__ Bm,
                                         float* __restrict__ Cm, int M, int N, int K, int ldc,
                                         const float* __restrict__ xn, const float* __restrict__ yn,
                                         int nb, int mb) {
  const int tid = threadIdx.x;
  const int m0 = mb * 64, n0 = nb * 64;
  const int tx = tid & 15, ty4 = tid >> 4;
  const int ar = tid >> 2, ak = (tid & 3) << 2;
  const int bk = tid >> 4, bn = (tid & 15) << 2;
  double acc[4][4] = {};
  for (int k0 = 0; k0 < K; k0 += 16) {
    float4 a4 = *(const float4*)(A + (size_t)(m0 + ar) * K + k0 + ak);
    As[ak + 0][ar] = (double)a4.x; As[ak + 1][ar] = (double)a4.y;
    As[ak + 2][ar] = (double)a4.z; As[ak + 3][ar] = (double)a4.w;
    float4 b4 = make_float4(0.f, 0.f, 0.f, 0.f);
    if (n0 + bn < N) b4 = *(const float4*)(Bm + (size_t)(k0 + bk) * N + n0 + bn);
    Bs[bk][bn + 0] = (double)b4.x; Bs[bk][bn + 1] = (double)b4.y;
    Bs[bk][bn + 2] = (double)b4.z; Bs[bk][bn + 3] = (double)b4.w;
    __syncthreads();
#pragma unroll
    for (int kk = 0; kk < 16; ++kk) {
      double av[4], bv[4];
#pragma unroll
      for (int i = 0; i < 4; ++i) av[i] = As[kk][ty4 + i * 16];
#pragma unroll
      for (int j = 0; j < 4; ++j) bv[j] = Bs[kk][tx + j * 16];
#pragma unroll
      for (int i = 0; i < 4; ++i)
#pragma unroll
        for (int j = 0; j < 4; ++j)
          acc[i][j] = fma(av[i], bv[j], acc[i][j]);
    }
    __syncthreads();
  }
#pragma unroll
  for (int i = 0; i < 4; ++i) {
    int row = m0 + ty4 + i * 16;
#pragma unroll
    for (int j = 0; j < 4; ++j) {
      int col = n0 + tx + j * 16;
      if (col >= N) continue;
      double d = acc[i][j] / ((double)xn[row] * (double)yn[col]);
      Cm[(size_t)row * ldc + col] = (float)d;
    }
  }
}

// ---- top-5 per row (one wave per row; 4 rows per block) ----
__device__ __forceinline__ void dev_topk(const float* __restrict__ sims,
                                         float* __restrict__ top_sims, float* __restrict__ top_idx,
                                         int rowblock) {
  int lane = threadIdx.x & 63, wave = threadIdx.x >> 6;
  int row = rowblock * 4 + wave;
  const float* s = sims + (size_t)row * 1000;
  float v[16];
  int idx[16];
#pragma unroll
  for (int t = 0; t < 16; ++t) {
    int c = lane + t * 64;
    if (c < 1000) { v[t] = s[c]; idx[t] = c; }
    else { v[t] = -1e30f; idx[t] = 1 << 20; }
  }
  for (int j = 0; j < 5; ++j) {
    float bv = -1e30f; int bi = 1 << 20;
#pragma unroll
    for (int t = 0; t < 16; ++t) {
      if (v[t] > bv || (v[t] == bv && idx[t] < bi)) { bv = v[t]; bi = idx[t]; }
    }
    float rv = bv; int ri = bi;
#pragma unroll
    for (int off = 32; off; off >>= 1) {
      float ov = __shfl_xor(rv, off);
      int oi = __shfl_xor(ri, off);
      if (ov > rv || (ov == rv && oi < ri)) { rv = ov; ri = oi; }
    }
    if (lane == 0) {
      top_sims[(size_t)row * 5 + j] = rv;
      top_idx[(size_t)row * 5 + j] = (float)ri;
    }
#pragma unroll
    for (int t = 0; t < 16; ++t)
      if (idx[t] == ri) v[t] = -1e30f;
  }
}

// ================= fused launches =================

// launch 1: trW1(128) | trW2(64) | trW3(96) | cmag(1000) | mag(2048)  = 3336 blocks
__global__ __launch_bounds__(256) void k_pre(const float* W1, __hip_bfloat16* w1t,
                                             const float* W2, __hip_bfloat16* w2t,
                                             const float* W3, __hip_bfloat16* w3t,
                                             const float* cre, const float* cim, float* cmagT, float* yn,
                                             const float* sre, const float* simg, float* mag,
                                             __hip_bfloat16* xcat, float* xn) {
  __shared__ float t32[64][65];
  __shared__ double red[4];
  int bid = blockIdx.x;
  if (bid < 128) {
    dev_tr<0>(t32, W1, (void*)w1t, 1024, 512, bid & 7, bid >> 3);
  } else if (bid < 192) {
    int t = bid - 128;
    dev_tr<0>(t32, W2, (void*)w2t, 512, 512, t & 7, t >> 3);
  } else if (bid < 288) {
    int t = bid - 192;
    dev_tr<0>(t32, W3, (void*)w3t, 512, 768, t % 12, t / 12);
  } else if (bid < 1288) {
    dev_cmag(red, cre, cim, cmagT, yn, bid - 288);
  } else {
    dev_mag(red, sre, simg, mag, xcat, xn, bid - 1288);
  }
}

// launch 2: MLP-L1 (64) | dots (512) | trW4 fp8 (9408)
union L1W4Smem {
  struct { short Al[128 * 32]; short Bl[128 * 32]; } m;
  float t32[64][65];
  struct { double As[16][65]; double Bs[16][65]; } d;
};
__global__ __launch_bounds__(256) void k_l1w4(const __hip_bfloat16* xcat, const __hip_bfloat16* w1t,
                                              __hip_bfloat16* h1b, const float* b1,
                                              const float* W4, unsigned char* w4f8,
                                              const float* mag, const float* cmagT, float* simsb,
                                              const float* xn, const float* yn) {
  __shared__ L1W4Smem sm;
  int bid = blockIdx.x;
  if (bid < 64) {
    dev_mlp<0>(sm.m.Al, sm.m.Bl, xcat, w1t, (void*)h1b, 2048, 512, 1024, 512, b1, bid & 3, bid >> 2);
  } else if (bid < 576) {
    int id = bid - 64;  // 0..511
    dev_dots(sm.d.As, sm.d.Bs, mag, cmagT, simsb, 2048, 1000, 512, 1000, xn, yn,
             id & 15, id >> 4);
  } else {
    int t = bid - 576;
    dev_tr<1>(sm.t32, W4, (void*)w4f8, 768, 50000, t % 784, t / 784);
  }
}

// launch 3: MLP-L2 (64, bf16 out) | topk (512)
__global__ __launch_bounds__(256) void k_l2topk(const __hip_bfloat16* h1b, const __hip_bfloat16* w2t,
                                                __hip_bfloat16* h2b, const float* b2,
                                                const float* simsb, float* top_sims, float* top_idx) {
  __shared__ short Al[128 * 32];
  __shared__ short Bl[128 * 32];
  int bid = blockIdx.x;
  if (bid < 64) {
    dev_mlp<0>(Al, Bl, h1b, w2t, (void*)h2b, 2048, 512, 512, 512, b2, bid & 3, bid >> 2);
  } else {
    dev_topk(simsb, top_sims, top_idx, bid - 64);
  }
}

// launch 4: MLP-L3 (fp8 out)
__global__ __launch_bounds__(256) void k_l3(const __hip_bfloat16* h2b, const __hip_bfloat16* w3t,
                                            unsigned char* h3f8, const float* b3) {
  __shared__ short Al[128 * 32];
  __shared__ short Bl[128 * 32];
  dev_mlp<1>(Al, Bl, h2b, w3t, (void*)h3f8, 2048, 768, 512, 768, b3, blockIdx.x % 6, blockIdx.x / 6);
}

// launch 5: final-layer GEMM — MX-scaled fp8 (unity scales; numerics HW-verified r13/r14).
// Occupancy fix: 256 THREADS (4 waves, 2M x 2N), per-wave 128x64 = 4q x 2p of 32x32 tiles,
// acc = f32x16[4][2] = 128 VGPR; with 256-thr blocks, 2 blocks/CU = 8 waves/CU allows the
// 256-VGPR cap (r13: 512thr+4/SIMD capped at 128 -> spill; r14: 512thr "cap 256" still means
// 16 waves/CU -> HW pool limits wave to 128 -> spill). This is r9's exact proven occupancy.
// Staging r9-identical: 6 VMEM/thread/K-tile, counted vmcnt(6), dbuf 48KB, same swizzle/grid.
__global__ __launch_bounds__(256, 2) void k_main(const unsigned char* __restrict__ A8,
                                                 const unsigned char* __restrict__ B8,
                                                 float* __restrict__ C, const float* __restrict__ bias) {
  const int KNT = 12;
  const int Kd = 768, Nd = 50000, ldc = 50000;
  __shared__ unsigned char As[2][16384];  // 256 rows x 64 B
  __shared__ unsigned char Bs[2][8192];   // 128 rows x 64 B
  const int tid = threadIdx.x, lane = tid & 63, wave = tid >> 6;
  const int wm = wave >> 1, wn = wave & 1;  // 2M x 2N waves, per-wave 128x64

  const int xcd = blockIdx.x & 7, j = blockIdx.x >> 3;
  const int mt = j & 7;
  const int ntile = xcd + 8 * (j >> 3);
  const int m0 = mt * 256, n0 = ntile * 128;

  f32x16 acc[4][2];
#pragma unroll
  for (int q = 0; q < 4; ++q)
#pragma unroll
    for (int p = 0; p < 2; ++p)
#pragma unroll
      for (int r = 0; r < 16; ++r) acc[q][p][r] = 0.f;

  // stage K-tile kt: A 4 gloads/thread, B 2 gloads/thread (6 VMEM/thread/K-tile)
  auto stageA = [&](int kt, int buf) {
    if (kt >= KNT) return;
    const int k0 = kt * 64;
#pragma unroll
    for (int r = 0; r < 4; ++r) {
      int idx = r * 256 + tid;           // 0..1023 16B-chunks
      int row = idx >> 2, c = idx & 3;
      int src = ((c * 2) ^ (row & 6)) * 8;  // 16B-contiguous (row&6 even)
      gload_lds16(A8 + (size_t)(m0 + row) * Kd + k0 + src, &As[buf][row * 64 + c * 16]);
    }
  };
  auto stageB = [&](int kt, int buf) {
    if (kt >= KNT) return;
    const int k0 = kt * 64;
#pragma unroll
    for (int r = 0; r < 2; ++r) {
      int idx = r * 256 + tid;           // 0..511
      int row = idx >> 2, c = idx & 3;
      int src = ((c * 2) ^ (row & 6)) * 8;
      gload_lds16(B8 + (size_t)(n0 + row) * Kd + k0 + src, &Bs[buf][row * 64 + c * 16]);
    }
  };

  // load one 32B operand (8 VGPRs) from swizzled LDS row; kh4 = (lane>>5)*4
  const int kh4 = (lane >> 5) * 4;
  auto ld32 = [&](const unsigned char* base, int row) -> i32x8 {
    i32x8 v;
#pragma unroll
    for (int i = 0; i < 4; ++i) {
      int slot = (kh4 + i) ^ (row & 6);
      const int* p32 = (const int*)(base + row * 64 + slot * 8);
      v[2 * i] = p32[0];
      v[2 * i + 1] = p32[1];
    }
    return v;
  };

  stageA(0, 0); stageB(0, 0);
  stageA(1, 1); stageB(1, 1);

  for (int g = 0; g < KNT; ++g) {
    const int buf = g & 1;
    if (g < KNT - 1) asm volatile("s_waitcnt vmcnt(6)" ::: "memory");  // tile g landed
    else             asm volatile("s_waitcnt vmcnt(0)" ::: "memory");
    __builtin_amdgcn_sched_barrier(0);
    __builtin_amdgcn_s_barrier();
    __builtin_amdgcn_sched_barrier(0);

    // src0 = B fragment: "row"(N) = wn*64 + p*32 + (lane&31), k-bytes kh4*8..+31
    i32x8 bfr[2];
#pragma unroll
    for (int p = 0; p < 2; ++p)
      bfr[p] = ld32(&Bs[buf][0], wn * 64 + p * 32 + (lane & 31));
    __builtin_amdgcn_s_setprio(1);
#pragma unroll
    for (int q = 0; q < 4; ++q) {
      i32x8 af = ld32(&As[buf][0], wm * 128 + q * 32 + (lane & 31));
#pragma unroll
      for (int p = 0; p < 2; ++p)
        acc[q][p] = __builtin_amdgcn_mfma_scale_f32_32x32x64_f8f6f4(
            bfr[p], af, acc[q][p], 0, 0, 0, 0x7f7f7f7f, 0, 0x7f7f7f7f);
    }
    __builtin_amdgcn_s_setprio(0);

    __builtin_amdgcn_sched_barrier(0);
    __builtin_amdgcn_s_barrier();
    __builtin_amdgcn_sched_barrier(0);
    stageA(g + 2, buf);
    stageB(g + 2, buf);
  }

  // epilogue: bias + 32 guarded float4 stores (M-row = lane&31 of tile; N-cols 4*(lane>>5)+8*r2+{0..3})
  const int nqo = 4 * (lane >> 5);
  float4 bias4[2][4];
#pragma unroll
  for (int p = 0; p < 2; ++p)
#pragma unroll
    for (int r2 = 0; r2 < 4; ++r2) {
      int colbase = n0 + wn * 64 + p * 32 + nqo + 8 * r2;
      bias4[p][r2] = (colbase < Nd) ? *(const float4*)(bias + colbase)
                                    : make_float4(0.f, 0.f, 0.f, 0.f);
    }
#pragma unroll
  for (int q = 0; q < 4; ++q) {
    int row = m0 + wm * 128 + q * 32 + (lane & 31);
#pragma unroll
    for (int p = 0; p < 2; ++p) {
#pragma unroll
      for (int r2 = 0; r2 < 4; ++r2) {
        int colbase = n0 + wn * 64 + p * 32 + nqo + 8 * r2;
        if (colbase < Nd) {
          float4 o = make_float4(acc[q][p][r2 * 4 + 0] + bias4[p][r2].x,
                                 acc[q][p][r2 * 4 + 1] + bias4[p][r2].y,
                                 acc[q][p][r2 * 4 + 2] + bias4[p][r2].z,
                                 acc[q][p][r2 * 4 + 3] + bias4[p][r2].w);
          *(float4*)(&C[(size_t)row * ldc + colbase]) = o;
        }
      }
    }
  }
}

extern "C" void kernel_launch(void* const* d_in, const int* in_sizes, int n_in,
                              void* d_out, int out_size, void* d_ws, size_t ws_size,
                              hipStream_t stream) {
  const float* sre = (const float*)d_in[0];
  const float* simg = (const float*)d_in[1];
  const float* cre = (const float*)d_in[2];
  const float* cim = (const float*)d_in[3];
  const float* W1 = (const float*)d_in[4];
  const float* b1 = (const float*)d_in[5];
  const float* W2 = (const float*)d_in[6];
  const float* b2 = (const float*)d_in[7];
  const float* W3 = (const float*)d_in[8];
  const float* b3 = (const float*)d_in[9];
  const float* W4 = (const float*)d_in[10];
  const float* b4 = (const float*)d_in[11];

  const int M = 2048, D = 512, Cc = 1000, V = 50000, K1 = 1024, H3 = 768;
  const int Npad2 = 392 * 128;  // 50176

  char* ws = (char*)d_ws;
  size_t off = 0;
  auto alloc = [&](size_t bytes) {
    char* p = ws + off;
    off = (off + bytes + 255) & ~(size_t)255;
    return p;
  };
  __hip_bfloat16* xcatb = (__hip_bfloat16*)alloc((size_t)M * K1 * 2);
  float* mag = (float*)alloc((size_t)M * D * 4);
  float* cmagT = (float*)alloc((size_t)D * Cc * 4);
  float* xn = (float*)alloc((size_t)M * 4);
  float* yn = (float*)alloc((size_t)Cc * 4);
  float* simsb = (float*)alloc((size_t)M * Cc * 4);
  __hip_bfloat16* h1b = (__hip_bfloat16*)alloc((size_t)M * 512 * 2);
  __hip_bfloat16* h2b = (__hip_bfloat16*)alloc((size_t)M * 512 * 2);
  unsigned char* h3f8 = (unsigned char*)alloc((size_t)M * H3);
  __hip_bfloat16* w1t = (__hip_bfloat16*)alloc((size_t)512 * K1 * 2);
  __hip_bfloat16* w2t = (__hip_bfloat16*)alloc((size_t)512 * 512 * 2);
  __hip_bfloat16* w3t = (__hip_bfloat16*)alloc((size_t)H3 * 512 * 2);
  unsigned char* w4f8 = (unsigned char*)alloc((size_t)Npad2 * H3);

  float* top_sims = (float*)d_out;
  float* top_idx = (float*)d_out + (size_t)M * 5;
  float* logits = (float*)d_out + (size_t)M * 5 * 2;

  // 1: weight transposes W1-3 + cmag + mag (all independent)
  k_pre<<<dim3(3336), dim3(256), 0, stream>>>(W1, w1t, W2, w2t, W3, w3t,
                                              cre, cim, cmagT, yn, sre, simg, mag, xcatb, xn);
  // 2: MLP-L1 + dots + W4 transpose
  k_l1w4<<<dim3(64 + 512 + 9408), dim3(256), 0, stream>>>(xcatb, w1t, h1b, b1, W4, w4f8,
                                                          mag, cmagT, simsb, xn, yn);
  // 3: MLP-L2 + top-k
  k_l2topk<<<dim3(64 + 512), dim3(256), 0, stream>>>(h1b, w2t, h2b, b2, simsb, top_sims, top_idx);
  // 4: MLP-L3
  k_l3<<<dim3(96), dim3(256), 0, stream>>>(h2b, w3t, h3f8, b3);
  // 5: big GEMM (MX-scaled fp8, 256 thr, 2 blocks/CU, acc fits 256-VGPR cap)
  k_main<<<dim3(3136), dim3(256), 0, stream>>>(h3f8, w4f8, logits, b4);
}

// Round 16
// 408.388 us; speedup vs baseline: 2.6957x; 2.6957x over previous
//
#include <hip/hip_runtime.h>
#include <hip/hip_bf16.h>
#include <hip/hip_fp8.h>

#define CEPS 1e-8f

typedef __attribute__((ext_vector_type(8))) __bf16 bf16x8;
typedef __attribute__((ext_vector_type(4))) float f32x4;

__device__ __forceinline__ void gload_lds16(const void* g, void* l) {
  __builtin_amdgcn_global_load_lds((const __attribute__((address_space(1))) unsigned int*)g,
                                   (__attribute__((address_space(3))) unsigned int*)l, 16, 0, 0);
}

__device__ __forceinline__ float gelu_f(float v) {
  return 0.5f * v * (1.0f + erff(v * 0.70710678118654752f));
}

__device__ __forceinline__ unsigned char f32_to_e4m3(float v) {
  __hip_fp8_e4m3 t(v);
  return (unsigned char)t.__x;
}

// ================= device bodies =================

// ---- magnitude + concat(bf16) + row norm ----
__device__ __forceinline__ void dev_mag(double* red, const float* __restrict__ re,
                                        const float* __restrict__ im, float* __restrict__ mag,
                                        __hip_bfloat16* __restrict__ xcat, float* __restrict__ xn,
                                        int row) {
  const float* r = re + (size_t)row * 512;
  const float* q = im + (size_t)row * 512;
  double ss = 0.0;
  for (int d = threadIdx.x; d < 512; d += 256) {
    float a = r[d], b = q[d];
    float s = __fadd_rn(__fmul_rn(a, a), __fmul_rn(b, b));  // match np rounding
    float m = __fsqrt_rn(s);
    mag[(size_t)row * 512 + d] = m;
    xcat[(size_t)row * 1024 + d] = __float2bfloat16(a);
    xcat[(size_t)row * 1024 + 512 + d] = __float2bfloat16(b);
    ss += (double)m * (double)m;
  }
  for (int off = 32; off; off >>= 1) ss += __shfl_xor(ss, off);
  int lane = threadIdx.x & 63, wave = threadIdx.x >> 6;
  if (lane == 0) red[wave] = ss;
  __syncthreads();
  if (threadIdx.x == 0) {
    double tot = red[0] + red[1] + red[2] + red[3];
    float n = (float)sqrt(tot);
    xn[row] = fmaxf(n, CEPS);
  }
}

// ---- concept magnitude (transposed) + norms ----
__device__ __forceinline__ void dev_cmag(double* red, const float* __restrict__ cre,
                                         const float* __restrict__ cim, float* __restrict__ cmagT,
                                         float* __restrict__ yn, int c) {
  const float* r = cre + (size_t)c * 512;
  const float* q = cim + (size_t)c * 512;
  double ss = 0.0;
  for (int d = threadIdx.x; d < 512; d += 256) {
    float a = r[d], b = q[d];
    float s = __fadd_rn(__fmul_rn(a, a), __fmul_rn(b, b));
    float m = __fsqrt_rn(s);
    cmagT[(size_t)d * 1000 + c] = m;
    ss += (double)m * (double)m;
  }
  for (int off = 32; off; off >>= 1) ss += __shfl_xor(ss, off);
  int lane = threadIdx.x & 63, wave = threadIdx.x >> 6;
  if (lane == 0) red[wave] = ss;
  __syncthreads();
  if (threadIdx.x == 0) {
    double tot = red[0] + red[1] + red[2] + red[3];
    float n = (float)sqrt(tot);
    yn[c] = fmaxf(n, CEPS);
  }
}

// ---- transpose: W[K,N] f32 -> Wt[n][k] (OUTT 0=bf16, 1=fp8; zero-pad n>=N) ----
template <int OUTT>
__device__ __forceinline__ void dev_tr(float (*t32)[65], const float* __restrict__ W,
                                       void* __restrict__ Wt, int K, int N, int bx, int by) {
  int n0 = bx * 64, k0 = by * 64;
  int tid = threadIdx.x;
  {
    int nc = tid & 15, kr4 = tid >> 4;
#pragma unroll
    for (int p = 0; p < 4; ++p) {
      int kr = p * 16 + kr4;
      int n = n0 + nc * 4;
      float4 v = make_float4(0.f, 0.f, 0.f, 0.f);
      if (n < N) v = *(const float4*)(W + (size_t)(k0 + kr) * N + n);
      t32[kr][nc * 4 + 0] = v.x; t32[kr][nc * 4 + 1] = v.y;
      t32[kr][nc * 4 + 2] = v.z; t32[kr][nc * 4 + 3] = v.w;
    }
  }
  __syncthreads();
  {
    int kc = tid & 15, nr4 = tid >> 4;
#pragma unroll
    for (int p = 0; p < 4; ++p) {
      int nr = p * 16 + nr4;
      if (OUTT == 0) {
        ushort4 o;
        __hip_bfloat16 h0 = __float2bfloat16(t32[kc * 4 + 0][nr]);
        __hip_bfloat16 h1 = __float2bfloat16(t32[kc * 4 + 1][nr]);
        __hip_bfloat16 h2 = __float2bfloat16(t32[kc * 4 + 2][nr]);
        __hip_bfloat16 h3 = __float2bfloat16(t32[kc * 4 + 3][nr]);
        o.x = *(unsigned short*)&h0; o.y = *(unsigned short*)&h1;
        o.z = *(unsigned short*)&h2; o.w = *(unsigned short*)&h3;
        *(ushort4*)((unsigned short*)Wt + (size_t)(n0 + nr) * K + k0 + kc * 4) = o;
      } else {
        unsigned int o = (unsigned int)f32_to_e4m3(t32[kc * 4 + 0][nr]) |
                         ((unsigned int)f32_to_e4m3(t32[kc * 4 + 1][nr]) << 8) |
                         ((unsigned int)f32_to_e4m3(t32[kc * 4 + 2][nr]) << 16) |
                         ((unsigned int)f32_to_e4m3(t32[kc * 4 + 3][nr]) << 24);
        *(unsigned int*)((unsigned char*)Wt + (size_t)(n0 + nr) * K + k0 + kc * 4) = o;
      }
    }
  }
}

// ---- 128x128 bf16 MFMA GEMM with gelu epilogue (MLP layers) ----
template <int OUTT>
__device__ __forceinline__ void dev_mlp(short* Al, short* Bl, const __hip_bfloat16* __restrict__ A,
                                        const __hip_bfloat16* __restrict__ Bt, void* __restrict__ C,
                                        int M, int N, int K, int ldc, const float* __restrict__ bias,
                                        int bx, int by) {
  const int tid = threadIdx.x, lane = tid & 63, wave = tid >> 6;
  const int m0 = by * 128, n0 = bx * 128;
  const int wr = wave >> 1, wc = wave & 1;
  f32x4 acc[4][4];
  f32x4 zero4 = {0.f, 0.f, 0.f, 0.f};
#pragma unroll
  for (int i = 0; i < 4; ++i)
#pragma unroll
    for (int j = 0; j < 4; ++j) acc[i][j] = zero4;

  const short* Ag = (const short*)A;
  const short* Bg = (const short*)Bt;
  for (int k0 = 0; k0 < K; k0 += 32) {
#pragma unroll
    for (int s = 0; s < 2; ++s) {
      int seg = wave + s * 4;
      int elem = seg * 512 + lane * 8;
      int row = elem >> 5, kk = elem & 31;
      gload_lds16(Ag + (size_t)(m0 + row) * K + k0 + kk, Al + elem);
      gload_lds16(Bg + (size_t)(n0 + row) * K + k0 + kk, Bl + elem);
    }
    __syncthreads();
    bf16x8 af[4], bfr[4];
    const int fr = lane & 15, fk = (lane >> 4) << 3;
#pragma unroll
    for (int i = 0; i < 4; ++i)
      af[i] = *(const bf16x8*)(Al + (wr * 64 + i * 16 + fr) * 32 + fk);
#pragma unroll
    for (int j = 0; j < 4; ++j)
      bfr[j] = *(const bf16x8*)(Bl + (wc * 64 + j * 16 + fr) * 32 + fk);
#pragma unroll
    for (int i = 0; i < 4; ++i)
#pragma unroll
      for (int j = 0; j < 4; ++j)
        acc[i][j] = __builtin_amdgcn_mfma_f32_16x16x32_bf16(af[i], bfr[j], acc[i][j], 0, 0, 0);
    __syncthreads();
  }
  const int fr = lane & 15, fq = lane >> 4;
#pragma unroll
  for (int j = 0; j < 4; ++j) {
    int col = n0 + wc * 64 + j * 16 + fr;
    if (col >= N) continue;
    float bv = bias[col];
#pragma unroll
    for (int i = 0; i < 4; ++i) {
      int rbase = m0 + wr * 64 + i * 16 + fq * 4;
#pragma unroll
      for (int r = 0; r < 4; ++r) {
        float v = gelu_f(acc[i][j][r] + bv);
        if (OUTT == 0)
          ((__hip_bfloat16*)C)[(size_t)(rbase + r) * ldc + col] = __float2bfloat16(v);
        else
          ((unsigned char*)C)[(size_t)(rbase + r) * ldc + col] = f32_to_e4m3(v);
      }
    }
  }
}

// ---- dots GEMM, f64 acc; LDS padded [16][65] (conflict-free); FMA order = rounds 7-15 ----
__device__ __forceinline__ void dev_dots(double (*As)[65], double (*Bs)[65],
                                         const float* __restrict__ A, const float* __restrict__ Bm,
                                         float* __restrict__ Cm, int M, int N, int K, int ldc,
                                         const float* __restrict__ xn, const float* __restrict__ yn,
                                         int nb, int mb) {
  const int tid = threadIdx.x;
  const int m0 = mb * 64, n0 = nb * 64;
  const int tx = tid & 15, ty4 = tid >> 4;
  const int ar = tid >> 2, ak = (tid & 3) << 2;
  const int bk = tid >> 4, bn = (tid & 15) << 2;
  double acc[4][4] = {};
  for (int k0 = 0; k0 < K; k0 += 16) {
    float4 a4 = *(const float4*)(A + (size_t)(m0 + ar) * K + k0 + ak);
    As[ak + 0][ar] = (double)a4.x; As[ak + 1][ar] = (double)a4.y;
    As[ak + 2][ar] = (double)a4.z; As[ak + 3][ar] = (double)a4.w;
    float4 b4 = make_float4(0.f, 0.f, 0.f, 0.f);
    if (n0 + bn < N) b4 = *(const float4*)(Bm + (size_t)(k0 + bk) * N + n0 + bn);
    Bs[bk][bn + 0] = (double)b4.x; Bs[bk][bn + 1] = (double)b4.y;
    Bs[bk][bn + 2] = (double)b4.z; Bs[bk][bn + 3] = (double)b4.w;
    __syncthreads();
#pragma unroll
    for (int kk = 0; kk < 16; ++kk) {
      double av[4], bv[4];
#pragma unroll
      for (int i = 0; i < 4; ++i) av[i] = As[kk][ty4 + i * 16];
#pragma unroll
      for (int j = 0; j < 4; ++j) bv[j] = Bs[kk][tx + j * 16];
#pragma unroll
      for (int i = 0; i < 4; ++i)
#pragma unroll
        for (int j = 0; j < 4; ++j)
          acc[i][j] = fma(av[i], bv[j], acc[i][j]);
    }
    __syncthreads();
  }
#pragma unroll
  for (int i = 0; i < 4; ++i) {
    int row = m0 + ty4 + i * 16;
#pragma unroll
    for (int j = 0; j < 4; ++j) {
      int col = n0 + tx + j * 16;
      if (col >= N) continue;
      double d = acc[i][j] / ((double)xn[row] * (double)yn[col]);
      Cm[(size_t)row * ldc + col] = (float)d;
    }
  }
}

// ---- top-5 per row (one wave per row; 4 rows per block) ----
__device__ __forceinline__ void dev_topk(const float* __restrict__ sims,
                                         float* __restrict__ top_sims, float* __restrict__ top_idx,
                                         int rowblock) {
  int lane = threadIdx.x & 63, wave = threadIdx.x >> 6;
  int row = rowblock * 4 + wave;
  const float* s = sims + (size_t)row * 1000;
  float v[16];
  int idx[16];
#pragma unroll
  for (int t = 0; t < 16; ++t) {
    int c = lane + t * 64;
    if (c < 1000) { v[t] = s[c]; idx[t] = c; }
    else { v[t] = -1e30f; idx[t] = 1 << 20; }
  }
  for (int j = 0; j < 5; ++j) {
    float bv = -1e30f; int bi = 1 << 20;
#pragma unroll
    for (int t = 0; t < 16; ++t) {
      if (v[t] > bv || (v[t] == bv && idx[t] < bi)) { bv = v[t]; bi = idx[t]; }
    }
    float rv = bv; int ri = bi;
#pragma unroll
    for (int off = 32; off; off >>= 1) {
      float ov = __shfl_xor(rv, off);
      int oi = __shfl_xor(ri, off);
      if (ov > rv || (ov == rv && oi < ri)) { rv = ov; ri = oi; }
    }
    if (lane == 0) {
      top_sims[(size_t)row * 5 + j] = rv;
      top_idx[(size_t)row * 5 + j] = (float)ri;
    }
#pragma unroll
    for (int t = 0; t < 16; ++t)
      if (idx[t] == ri) v[t] = -1e30f;
  }
}

// ================= fused launches =================

// launch 1: trW1(128) | trW2(64) | trW3(96) | cmag(1000) | mag(2048) | trW4-fp8(9408) = 12744 blocks
// (trW4 depends only on input W4 -> moved here to overlap with the other pre-work)
__global__ __launch_bounds__(256) void k_pre(const float* W1, __hip_bfloat16* w1t,
                                             const float* W2, __hip_bfloat16* w2t,
                                             const float* W3, __hip_bfloat16* w3t,
                                             const float* cre, const float* cim, float* cmagT, float* yn,
                                             const float* sre, const float* simg, float* mag,
                                             __hip_bfloat16* xcat, float* xn,
                                             const float* W4, unsigned char* w4f8) {
  __shared__ float t32[64][65];
  __shared__ double red[4];
  int bid = blockIdx.x;
  if (bid < 128) {
    dev_tr<0>(t32, W1, (void*)w1t, 1024, 512, bid & 7, bid >> 3);
  } else if (bid < 192) {
    int t = bid - 128;
    dev_tr<0>(t32, W2, (void*)w2t, 512, 512, t & 7, t >> 3);
  } else if (bid < 288) {
    int t = bid - 192;
    dev_tr<0>(t32, W3, (void*)w3t, 512, 768, t % 12, t / 12);
  } else if (bid < 1288) {
    dev_cmag(red, cre, cim, cmagT, yn, bid - 288);
  } else if (bid < 3336) {
    dev_mag(red, sre, simg, mag, xcat, xn, bid - 1288);
  } else {
    int t = bid - 3336;
    dev_tr<1>(t32, W4, (void*)w4f8, 768, 50000, t % 784, t / 784);
  }
}

// launch 2: MLP-L1 (64) | dots (512)  = 576 blocks
union L1DSmem {
  struct { short Al[128 * 32]; short Bl[128 * 32]; } m;
  struct { double As[16][65]; double Bs[16][65]; } d;
};
__global__ __launch_bounds__(256) void k_l1d(const __hip_bfloat16* xcat, const __hip_bfloat16* w1t,
                                             __hip_bfloat16* h1b, const float* b1,
                                             const float* mag, const float* cmagT, float* simsb,
                                             const float* xn, const float* yn) {
  __shared__ L1DSmem sm;
  int bid = blockIdx.x;
  if (bid < 64) {
    dev_mlp<0>(sm.m.Al, sm.m.Bl, xcat, w1t, (void*)h1b, 2048, 512, 1024, 512, b1, bid & 3, bid >> 2);
  } else {
    int id = bid - 64;  // 0..511
    dev_dots(sm.d.As, sm.d.Bs, mag, cmagT, simsb, 2048, 1000, 512, 1000, xn, yn,
             id & 15, id >> 4);
  }
}

// launch 3: MLP-L2 (64, bf16 out) | topk (512)
__global__ __launch_bounds__(256) void k_l2topk(const __hip_bfloat16* h1b, const __hip_bfloat16* w2t,
                                                __hip_bfloat16* h2b, const float* b2,
                                                const float* simsb, float* top_sims, float* top_idx) {
  __shared__ short Al[128 * 32];
  __shared__ short Bl[128 * 32];
  int bid = blockIdx.x;
  if (bid < 64) {
    dev_mlp<0>(Al, Bl, h1b, w2t, (void*)h2b, 2048, 512, 512, 512, b2, bid & 3, bid >> 2);
  } else {
    dev_topk(simsb, top_sims, top_idx, bid - 64);
  }
}

// launch 4: MLP-L3 (fp8 out)
__global__ __launch_bounds__(256) void k_l3(const __hip_bfloat16* h2b, const __hip_bfloat16* w3t,
                                            unsigned char* h3f8, const float* b3) {
  __shared__ short Al[128 * 32];
  __shared__ short Bl[128 * 32];
  dev_mlp<1>(Al, Bl, h2b, w3t, (void*)h3f8, 2048, 768, 512, 768, b3, blockIdx.x % 6, blockIdx.x / 6);
}

// launch 5: final-layer fp8 GEMM — r12 config verbatim (best measured: 389.6us total).
// 256Mx128N tile, BK=64, dbuf 48KB LDS, 512 thr / 8 waves (4M x 2N, per-wave 64x64),
// counted vmcnt(3), source swizzle, swapped-operand MFMA, float4 C dump.
// MX variants (r13-r15) all spilled (acc 128 VGPR + operands cannot fit any >=2-waves/SIMD
// occupancy) -> abandoned; 16x16x32 fp8 with acc 64 VGPR is the stable point.
__global__ __launch_bounds__(512, 4) void k_main(const unsigned char* __restrict__ A8,
                                                 const unsigned char* __restrict__ B8,
                                                 float* __restrict__ C, const float* __restrict__ bias) {
  const int KNT = 12;
  const int Kd = 768, Nd = 50000, ldc = 50000;
  __shared__ unsigned char As[2][16384];  // 256 rows x 64 B
  __shared__ unsigned char Bs[2][8192];   // 128 rows x 64 B
  const int tid = threadIdx.x, lane = tid & 63, wave = tid >> 6;
  const int wm = wave & 3, wn = wave >> 2;  // 4M x 2N waves, per-wave 64x64

  const int xcd = blockIdx.x & 7, j = blockIdx.x >> 3;
  const int mt = j & 7;
  const int ntile = xcd + 8 * (j >> 3);
  const int m0 = mt * 256, n0 = ntile * 128;

  f32x4 acc[4][4];
  f32x4 z4 = {0.f, 0.f, 0.f, 0.f};
#pragma unroll
  for (int q = 0; q < 4; ++q)
#pragma unroll
    for (int p = 0; p < 4; ++p) acc[q][p] = z4;

  auto stageA = [&](int kt, int buf) {
    if (kt >= KNT) return;
    const int k0 = kt * 64;
#pragma unroll
    for (int r = 0; r < 2; ++r) {
      int idx = r * 512 + tid;           // 0..1023 16B-chunks
      int row = idx >> 2, c = idx & 3;
      int src = ((c * 2) ^ (row & 6)) * 8;  // 16B-contiguous (row&6 even)
      gload_lds16(A8 + (size_t)(m0 + row) * Kd + k0 + src, &As[buf][row * 64 + c * 16]);
    }
  };
  auto stageB = [&](int kt, int buf) {
    if (kt >= KNT) return;
    const int k0 = kt * 64;
    {
      int idx = tid;                     // 0..511
      int row = idx >> 2, c = idx & 3;
      int src = ((c * 2) ^ (row & 6)) * 8;
      gload_lds16(B8 + (size_t)(n0 + row) * Kd + k0 + src, &Bs[buf][row * 64 + c * 16]);
    }
  };

  stageA(0, 0); stageB(0, 0);
  stageA(1, 1); stageB(1, 1);

  for (int g = 0; g < KNT; ++g) {
    const int buf = g & 1;
    if (g < KNT - 1) asm volatile("s_waitcnt vmcnt(3)" ::: "memory");  // tile g landed
    else             asm volatile("s_waitcnt vmcnt(0)" ::: "memory");
    __builtin_amdgcn_sched_barrier(0);
    __builtin_amdgcn_s_barrier();
    __builtin_amdgcn_sched_barrier(0);

    long bfr[4][2];
#pragma unroll
    for (int p = 0; p < 4; ++p) {
      int row = wn * 64 + p * 16 + (lane & 15);
#pragma unroll
      for (int kh = 0; kh < 2; ++kh) {
        int slot = (kh * 4 + (lane >> 4)) ^ (row & 6);
        bfr[p][kh] = *(const long*)(&Bs[buf][row * 64 + slot * 8]);
      }
    }
    __builtin_amdgcn_s_setprio(1);
#pragma unroll
    for (int q = 0; q < 4; ++q) {
      int rowA = wm * 64 + q * 16 + (lane & 15);
      long af[2];
#pragma unroll
      for (int kh = 0; kh < 2; ++kh) {
        int slot = (kh * 4 + (lane >> 4)) ^ (rowA & 6);
        af[kh] = *(const long*)(&As[buf][rowA * 64 + slot * 8]);
      }
#pragma unroll
      for (int kh = 0; kh < 2; ++kh)
#pragma unroll
        for (int p = 0; p < 4; ++p)
          acc[q][p] = __builtin_amdgcn_mfma_f32_16x16x32_fp8_fp8(bfr[p][kh], af[kh], acc[q][p], 0, 0, 0);
    }
    __builtin_amdgcn_s_setprio(0);

    __builtin_amdgcn_sched_barrier(0);
    __builtin_amdgcn_s_barrier();
    __builtin_amdgcn_sched_barrier(0);
    stageA(g + 2, buf);
    stageB(g + 2, buf);
  }

  // epilogue: bias + float4 stores (swapped layout: per lane 1 row, 4 consecutive cols)
  const int colq = (lane >> 4) * 4;
  float4 bias4[4];
#pragma unroll
  for (int p = 0; p < 4; ++p) {
    int colbase = n0 + wn * 64 + p * 16 + colq;
    bias4[p] = (colbase < Nd) ? *(const float4*)(bias + colbase) : make_float4(0.f, 0.f, 0.f, 0.f);
  }
#pragma unroll
  for (int q = 0; q < 4; ++q) {
    int row = m0 + wm * 64 + q * 16 + (lane & 15);
#pragma unroll
    for (int p = 0; p < 4; ++p) {
      int colbase = n0 + wn * 64 + p * 16 + colq;
      if (colbase < Nd) {
        f32x4 v = acc[q][p];
        float4 o = make_float4(v[0] + bias4[p].x, v[1] + bias4[p].y,
                               v[2] + bias4[p].z, v[3] + bias4[p].w);
        *(float4*)(&C[(size_t)row * ldc + colbase]) = o;
      }
    }
  }
}

extern "C" void kernel_launch(void* const* d_in, const int* in_sizes, int n_in,
                              void* d_out, int out_size, void* d_ws, size_t ws_size,
                              hipStream_t stream) {
  const float* sre = (const float*)d_in[0];
  const float* simg = (const float*)d_in[1];
  const float* cre = (const float*)d_in[2];
  const float* cim = (const float*)d_in[3];
  const float* W1 = (const float*)d_in[4];
  const float* b1 = (const float*)d_in[5];
  const float* W2 = (const float*)d_in[6];
  const float* b2 = (const float*)d_in[7];
  const float* W3 = (const float*)d_in[8];
  const float* b3 = (const float*)d_in[9];
  const float* W4 = (const float*)d_in[10];
  const float* b4 = (const float*)d_in[11];

  const int M = 2048, D = 512, Cc = 1000, V = 50000, K1 = 1024, H3 = 768;
  const int Npad2 = 392 * 128;  // 50176

  char* ws = (char*)d_ws;
  size_t off = 0;
  auto alloc = [&](size_t bytes) {
    char* p = ws + off;
    off = (off + bytes + 255) & ~(size_t)255;
    return p;
  };
  __hip_bfloat16* xcatb = (__hip_bfloat16*)alloc((size_t)M * K1 * 2);
  float* mag = (float*)alloc((size_t)M * D * 4);
  float* cmagT = (float*)alloc((size_t)D * Cc * 4);
  float* xn = (float*)alloc((size_t)M * 4);
  float* yn = (float*)alloc((size_t)Cc * 4);
  float* simsb = (float*)alloc((size_t)M * Cc * 4);
  __hip_bfloat16* h1b = (__hip_bfloat16*)alloc((size_t)M * 512 * 2);
  __hip_bfloat16* h2b = (__hip_bfloat16*)alloc((size_t)M * 512 * 2);
  unsigned char* h3f8 = (unsigned char*)alloc((size_t)M * H3);
  __hip_bfloat16* w1t = (__hip_bfloat16*)alloc((size_t)512 * K1 * 2);
  __hip_bfloat16* w2t = (__hip_bfloat16*)alloc((size_t)512 * 512 * 2);
  __hip_bfloat16* w3t = (__hip_bfloat16*)alloc((size_t)H3 * 512 * 2);
  unsigned char* w4f8 = (unsigned char*)alloc((size_t)Npad2 * H3);

  float* top_sims = (float*)d_out;
  float* top_idx = (float*)d_out + (size_t)M * 5;
  float* logits = (float*)d_out + (size_t)M * 5 * 2;

  // 1: all input-only work: trW1-3, cmag, mag, trW4-fp8 (12744 blocks)
  k_pre<<<dim3(12744), dim3(256), 0, stream>>>(W1, w1t, W2, w2t, W3, w3t,
                                               cre, cim, cmagT, yn, sre, simg, mag, xcatb, xn,
                                               W4, w4f8);
  // 2: MLP-L1 + dots
  k_l1d<<<dim3(64 + 512), dim3(256), 0, stream>>>(xcatb, w1t, h1b, b1, mag, cmagT, simsb, xn, yn);
  // 3: MLP-L2 + top-k
  k_l2topk<<<dim3(64 + 512), dim3(256), 0, stream>>>(h1b, w2t, h2b, b2, simsb, top_sims, top_idx);
  // 4: MLP-L3
  k_l3<<<dim3(96), dim3(256), 0, stream>>>(h2b, w3t, h3f8, b3);
  // 5: big fp8 GEMM (r12 config)
  k_main<<<dim3(3136), dim3(512), 0, stream>>>(h3f8, w4f8, logits, b4);
}

// Round 17
// 386.127 us; speedup vs baseline: 2.8511x; 1.0577x over previous
//
#include <hip/hip_runtime.h>
#include <hip/hip_bf16.h>
#include <hip/hip_fp8.h>

#define CEPS 1e-8f

typedef __attribute__((ext_vector_type(8))) __bf16 bf16x8;
typedef __attribute__((ext_vector_type(4))) float f32x4;

__device__ __forceinline__ void gload_lds16(const void* g, void* l) {
  __builtin_amdgcn_global_load_lds((const __attribute__((address_space(1))) unsigned int*)g,
                                   (__attribute__((address_space(3))) unsigned int*)l, 16, 0, 0);
}

__device__ __forceinline__ float gelu_f(float v) {
  return 0.5f * v * (1.0f + erff(v * 0.70710678118654752f));
}

__device__ __forceinline__ unsigned char f32_to_e4m3(float v) {
  __hip_fp8_e4m3 t(v);
  return (unsigned char)t.__x;
}

// ================= device bodies =================

// ---- magnitude + concat(bf16) + row norm ----
__device__ __forceinline__ void dev_mag(double* red, const float* __restrict__ re,
                                        const float* __restrict__ im, float* __restrict__ mag,
                                        __hip_bfloat16* __restrict__ xcat, float* __restrict__ xn,
                                        int row) {
  const float* r = re + (size_t)row * 512;
  const float* q = im + (size_t)row * 512;
  double ss = 0.0;
  for (int d = threadIdx.x; d < 512; d += 256) {
    float a = r[d], b = q[d];
    float s = __fadd_rn(__fmul_rn(a, a), __fmul_rn(b, b));  // match np rounding
    float m = __fsqrt_rn(s);
    mag[(size_t)row * 512 + d] = m;
    xcat[(size_t)row * 1024 + d] = __float2bfloat16(a);
    xcat[(size_t)row * 1024 + 512 + d] = __float2bfloat16(b);
    ss += (double)m * (double)m;
  }
  for (int off = 32; off; off >>= 1) ss += __shfl_xor(ss, off);
  int lane = threadIdx.x & 63, wave = threadIdx.x >> 6;
  if (lane == 0) red[wave] = ss;
  __syncthreads();
  if (threadIdx.x == 0) {
    double tot = red[0] + red[1] + red[2] + red[3];
    float n = (float)sqrt(tot);
    xn[row] = fmaxf(n, CEPS);
  }
}

// ---- concept magnitude (transposed) + norms ----
__device__ __forceinline__ void dev_cmag(double* red, const float* __restrict__ cre,
                                         const float* __restrict__ cim, float* __restrict__ cmagT,
                                         float* __restrict__ yn, int c) {
  const float* r = cre + (size_t)c * 512;
  const float* q = cim + (size_t)c * 512;
  double ss = 0.0;
  for (int d = threadIdx.x; d < 512; d += 256) {
    float a = r[d], b = q[d];
    float s = __fadd_rn(__fmul_rn(a, a), __fmul_rn(b, b));
    float m = __fsqrt_rn(s);
    cmagT[(size_t)d * 1000 + c] = m;
    ss += (double)m * (double)m;
  }
  for (int off = 32; off; off >>= 1) ss += __shfl_xor(ss, off);
  int lane = threadIdx.x & 63, wave = threadIdx.x >> 6;
  if (lane == 0) red[wave] = ss;
  __syncthreads();
  if (threadIdx.x == 0) {
    double tot = red[0] + red[1] + red[2] + red[3];
    float n = (float)sqrt(tot);
    yn[c] = fmaxf(n, CEPS);
  }
}

// ---- transpose: W[K,N] f32 -> Wt[n][k] (OUTT 0=bf16, 1=fp8; zero-pad n>=N) ----
template <int OUTT>
__device__ __forceinline__ void dev_tr(float (*t32)[65], const float* __restrict__ W,
                                       void* __restrict__ Wt, int K, int N, int bx, int by) {
  int n0 = bx * 64, k0 = by * 64;
  int tid = threadIdx.x;
  {
    int nc = tid & 15, kr4 = tid >> 4;
#pragma unroll
    for (int p = 0; p < 4; ++p) {
      int kr = p * 16 + kr4;
      int n = n0 + nc * 4;
      float4 v = make_float4(0.f, 0.f, 0.f, 0.f);
      if (n < N) v = *(const float4*)(W + (size_t)(k0 + kr) * N + n);
      t32[kr][nc * 4 + 0] = v.x; t32[kr][nc * 4 + 1] = v.y;
      t32[kr][nc * 4 + 2] = v.z; t32[kr][nc * 4 + 3] = v.w;
    }
  }
  __syncthreads();
  {
    int kc = tid & 15, nr4 = tid >> 4;
#pragma unroll
    for (int p = 0; p < 4; ++p) {
      int nr = p * 16 + nr4;
      if (OUTT == 0) {
        ushort4 o;
        __hip_bfloat16 h0 = __float2bfloat16(t32[kc * 4 + 0][nr]);
        __hip_bfloat16 h1 = __float2bfloat16(t32[kc * 4 + 1][nr]);
        __hip_bfloat16 h2 = __float2bfloat16(t32[kc * 4 + 2][nr]);
        __hip_bfloat16 h3 = __float2bfloat16(t32[kc * 4 + 3][nr]);
        o.x = *(unsigned short*)&h0; o.y = *(unsigned short*)&h1;
        o.z = *(unsigned short*)&h2; o.w = *(unsigned short*)&h3;
        *(ushort4*)((unsigned short*)Wt + (size_t)(n0 + nr) * K + k0 + kc * 4) = o;
      } else {
        unsigned int o = (unsigned int)f32_to_e4m3(t32[kc * 4 + 0][nr]) |
                         ((unsigned int)f32_to_e4m3(t32[kc * 4 + 1][nr]) << 8) |
                         ((unsigned int)f32_to_e4m3(t32[kc * 4 + 2][nr]) << 16) |
                         ((unsigned int)f32_to_e4m3(t32[kc * 4 + 3][nr]) << 24);
        *(unsigned int*)((unsigned char*)Wt + (size_t)(n0 + nr) * K + k0 + kc * 4) = o;
      }
    }
  }
}

// ---- 128x128 bf16 MFMA GEMM with gelu epilogue (MLP layers) ----
template <int OUTT>
__device__ __forceinline__ void dev_mlp(short* Al, short* Bl, const __hip_bfloat16* __restrict__ A,
                                        const __hip_bfloat16* __restrict__ Bt, void* __restrict__ C,
                                        int M, int N, int K, int ldc, const float* __restrict__ bias,
                                        int bx, int by) {
  const int tid = threadIdx.x, lane = tid & 63, wave = tid >> 6;
  const int m0 = by * 128, n0 = bx * 128;
  const int wr = wave >> 1, wc = wave & 1;
  f32x4 acc[4][4];
  f32x4 zero4 = {0.f, 0.f, 0.f, 0.f};
#pragma unroll
  for (int i = 0; i < 4; ++i)
#pragma unroll
    for (int j = 0; j < 4; ++j) acc[i][j] = zero4;

  const short* Ag = (const short*)A;
  const short* Bg = (const short*)Bt;
  for (int k0 = 0; k0 < K; k0 += 32) {
#pragma unroll
    for (int s = 0; s < 2; ++s) {
      int seg = wave + s * 4;
      int elem = seg * 512 + lane * 8;
      int row = elem >> 5, kk = elem & 31;
      gload_lds16(Ag + (size_t)(m0 + row) * K + k0 + kk, Al + elem);
      gload_lds16(Bg + (size_t)(n0 + row) * K + k0 + kk, Bl + elem);
    }
    __syncthreads();
    bf16x8 af[4], bfr[4];
    const int fr = lane & 15, fk = (lane >> 4) << 3;
#pragma unroll
    for (int i = 0; i < 4; ++i)
      af[i] = *(const bf16x8*)(Al + (wr * 64 + i * 16 + fr) * 32 + fk);
#pragma unroll
    for (int j = 0; j < 4; ++j)
      bfr[j] = *(const bf16x8*)(Bl + (wc * 64 + j * 16 + fr) * 32 + fk);
#pragma unroll
    for (int i = 0; i < 4; ++i)
#pragma unroll
      for (int j = 0; j < 4; ++j)
        acc[i][j] = __builtin_amdgcn_mfma_f32_16x16x32_bf16(af[i], bfr[j], acc[i][j], 0, 0, 0);
    __syncthreads();
  }
  const int fr = lane & 15, fq = lane >> 4;
#pragma unroll
  for (int j = 0; j < 4; ++j) {
    int col = n0 + wc * 64 + j * 16 + fr;
    if (col >= N) continue;
    float bv = bias[col];
#pragma unroll
    for (int i = 0; i < 4; ++i) {
      int rbase = m0 + wr * 64 + i * 16 + fq * 4;
#pragma unroll
      for (int r = 0; r < 4; ++r) {
        float v = gelu_f(acc[i][j][r] + bv);
        if (OUTT == 0)
          ((__hip_bfloat16*)C)[(size_t)(rbase + r) * ldc + col] = __float2bfloat16(v);
        else
          ((unsigned char*)C)[(size_t)(rbase + r) * ldc + col] = f32_to_e4m3(v);
      }
    }
  }
}

// ---- dots GEMM, f64 acc; LDS padded [16][65] (conflict-free); FMA order = rounds 7-16 ----
__device__ __forceinline__ void dev_dots(double (*As)[65], double (*Bs)[65],
                                         const float* __restrict__ A, const float* __restrict__ Bm,
                                         float* __restrict__ Cm, int M, int N, int K, int ldc,
                                         const float* __restrict__ xn, const float* __restrict__ yn,
                                         int nb, int mb) {
  const int tid = threadIdx.x;
  const int m0 = mb * 64, n0 = nb * 64;
  const int tx = tid & 15, ty4 = tid >> 4;
  const int ar = tid >> 2, ak = (tid & 3) << 2;
  const int bk = tid >> 4, bn = (tid & 15) << 2;
  double acc[4][4] = {};
  for (int k0 = 0; k0 < K; k0 += 16) {
    float4 a4 = *(const float4*)(A + (size_t)(m0 + ar) * K + k0 + ak);
    As[ak + 0][ar] = (double)a4.x; As[ak + 1][ar] = (double)a4.y;
    As[ak + 2][ar] = (double)a4.z; As[ak + 3][ar] = (double)a4.w;
    float4 b4 = make_float4(0.f, 0.f, 0.f, 0.f);
    if (n0 + bn < N) b4 = *(const float4*)(Bm + (size_t)(k0 + bk) * N + n0 + bn);
    Bs[bk][bn + 0] = (double)b4.x; Bs[bk][bn + 1] = (double)b4.y;
    Bs[bk][bn + 2] = (double)b4.z; Bs[bk][bn + 3] = (double)b4.w;
    __syncthreads();
#pragma unroll
    for (int kk = 0; kk < 16; ++kk) {
      double av[4], bv[4];
#pragma unroll
      for (int i = 0; i < 4; ++i) av[i] = As[kk][ty4 + i * 16];
#pragma unroll
      for (int j = 0; j < 4; ++j) bv[j] = Bs[kk][tx + j * 16];
#pragma unroll
      for (int i = 0; i < 4; ++i)
#pragma unroll
        for (int j = 0; j < 4; ++j)
          acc[i][j] = fma(av[i], bv[j], acc[i][j]);
    }
    __syncthreads();
  }
#pragma unroll
  for (int i = 0; i < 4; ++i) {
    int row = m0 + ty4 + i * 16;
#pragma unroll
    for (int j = 0; j < 4; ++j) {
      int col = n0 + tx + j * 16;
      if (col >= N) continue;
      double d = acc[i][j] / ((double)xn[row] * (double)yn[col]);
      Cm[(size_t)row * ldc + col] = (float)d;
    }
  }
}

// ---- top-5 per row (one wave per row; 4 rows per block) ----
__device__ __forceinline__ void dev_topk(const float* __restrict__ sims,
                                         float* __restrict__ top_sims, float* __restrict__ top_idx,
                                         int rowblock) {
  int lane = threadIdx.x & 63, wave = threadIdx.x >> 6;
  int row = rowblock * 4 + wave;
  const float* s = sims + (size_t)row * 1000;
  float v[16];
  int idx[16];
#pragma unroll
  for (int t = 0; t < 16; ++t) {
    int c = lane + t * 64;
    if (c < 1000) { v[t] = s[c]; idx[t] = c; }
    else { v[t] = -1e30f; idx[t] = 1 << 20; }
  }
  for (int j = 0; j < 5; ++j) {
    float bv = -1e30f; int bi = 1 << 20;
#pragma unroll
    for (int t = 0; t < 16; ++t) {
      if (v[t] > bv || (v[t] == bv && idx[t] < bi)) { bv = v[t]; bi = idx[t]; }
    }
    float rv = bv; int ri = bi;
#pragma unroll
    for (int off = 32; off; off >>= 1) {
      float ov = __shfl_xor(rv, off);
      int oi = __shfl_xor(ri, off);
      if (ov > rv || (ov == rv && oi < ri)) { rv = ov; ri = oi; }
    }
    if (lane == 0) {
      top_sims[(size_t)row * 5 + j] = rv;
      top_idx[(size_t)row * 5 + j] = (float)ri;
    }
#pragma unroll
    for (int t = 0; t < 16; ++t)
      if (idx[t] == ri) v[t] = -1e30f;
  }
}

// ================= fused launches (r12 structure — best measured 389.6us) =================

// launch 1: trW1(128) | trW2(64) | trW3(96) | cmag(1000) | mag(2048)  = 3336 blocks
__global__ __launch_bounds__(256) void k_pre(const float* W1, __hip_bfloat16* w1t,
                                             const float* W2, __hip_bfloat16* w2t,
                                             const float* W3, __hip_bfloat16* w3t,
                                             const float* cre, const float* cim, float* cmagT, float* yn,
                                             const float* sre, const float* simg, float* mag,
                                             __hip_bfloat16* xcat, float* xn) {
  __shared__ float t32[64][65];
  __shared__ double red[4];
  int bid = blockIdx.x;
  if (bid < 128) {
    dev_tr<0>(t32, W1, (void*)w1t, 1024, 512, bid & 7, bid >> 3);
  } else if (bid < 192) {
    int t = bid - 128;
    dev_tr<0>(t32, W2, (void*)w2t, 512, 512, t & 7, t >> 3);
  } else if (bid < 288) {
    int t = bid - 192;
    dev_tr<0>(t32, W3, (void*)w3t, 512, 768, t % 12, t / 12);
  } else if (bid < 1288) {
    dev_cmag(red, cre, cim, cmagT, yn, bid - 288);
  } else {
    dev_mag(red, sre, simg, mag, xcat, xn, bid - 1288);
  }
}

// launch 2: MLP-L1 (64) | dots (512, hidden under trW4's HBM stream) | trW4 fp8 (9408)
union L1W4Smem {
  struct { short Al[128 * 32]; short Bl[128 * 32]; } m;
  float t32[64][65];
  struct { double As[16][65]; double Bs[16][65]; } d;
};
__global__ __launch_bounds__(256) void k_l1w4(const __hip_bfloat16* xcat, const __hip_bfloat16* w1t,
                                              __hip_bfloat16* h1b, const float* b1,
                                              const float* W4, unsigned char* w4f8,
                                              const float* mag, const float* cmagT, float* simsb,
                                              const float* xn, const float* yn) {
  __shared__ L1W4Smem sm;
  int bid = blockIdx.x;
  if (bid < 64) {
    dev_mlp<0>(sm.m.Al, sm.m.Bl, xcat, w1t, (void*)h1b, 2048, 512, 1024, 512, b1, bid & 3, bid >> 2);
  } else if (bid < 576) {
    int id = bid - 64;  // 0..511
    dev_dots(sm.d.As, sm.d.Bs, mag, cmagT, simsb, 2048, 1000, 512, 1000, xn, yn,
             id & 15, id >> 4);
  } else {
    int t = bid - 576;
    dev_tr<1>(sm.t32, W4, (void*)w4f8, 768, 50000, t % 784, t / 784);
  }
}

// launch 3: MLP-L2 (64, bf16 out) | topk (512)
__global__ __launch_bounds__(256) void k_l2topk(const __hip_bfloat16* h1b, const __hip_bfloat16* w2t,
                                                __hip_bfloat16* h2b, const float* b2,
                                                const float* simsb, float* top_sims, float* top_idx) {
  __shared__ short Al[128 * 32];
  __shared__ short Bl[128 * 32];
  int bid = blockIdx.x;
  if (bid < 64) {
    dev_mlp<0>(Al, Bl, h1b, w2t, (void*)h2b, 2048, 512, 512, 512, b2, bid & 3, bid >> 2);
  } else {
    dev_topk(simsb, top_sims, top_idx, bid - 64);
  }
}

// launch 4: MLP-L3 (fp8 out)
__global__ __launch_bounds__(256) void k_l3(const __hip_bfloat16* h2b, const __hip_bfloat16* w3t,
                                            unsigned char* h3f8, const float* b3) {
  __shared__ short Al[128 * 32];
  __shared__ short Bl[128 * 32];
  dev_mlp<1>(Al, Bl, h2b, w3t, (void*)h3f8, 2048, 768, 512, 768, b3, blockIdx.x % 6, blockIdx.x / 6);
}

// launch 5: final-layer fp8 GEMM — r12 kernel + TRIPLE-buffered LDS (72KB, still 2 blocks/CU).
// Two K-tiles in flight (vmcnt(6) steady / 3 / 0 drain) -> 2x the latency-covering window
// at zero register cost. Everything else identical to r12 (best measured).
__global__ __launch_bounds__(512, 4) void k_main(const unsigned char* __restrict__ A8,
                                                 const unsigned char* __restrict__ B8,
                                                 float* __restrict__ C, const float* __restrict__ bias) {
  const int KNT = 12;
  const int Kd = 768, Nd = 50000, ldc = 50000;
  __shared__ unsigned char As[3][16384];  // 3 x 256 rows x 64 B
  __shared__ unsigned char Bs[3][8192];   // 3 x 128 rows x 64 B
  const int tid = threadIdx.x, lane = tid & 63, wave = tid >> 6;
  const int wm = wave & 3, wn = wave >> 2;  // 4M x 2N waves, per-wave 64x64

  const int xcd = blockIdx.x & 7, j = blockIdx.x >> 3;
  const int mt = j & 7;
  const int ntile = xcd + 8 * (j >> 3);
  const int m0 = mt * 256, n0 = ntile * 128;

  f32x4 acc[4][4];
  f32x4 z4 = {0.f, 0.f, 0.f, 0.f};
#pragma unroll
  for (int q = 0; q < 4; ++q)
#pragma unroll
    for (int p = 0; p < 4; ++p) acc[q][p] = z4;

  auto stageA = [&](int kt, int buf) {
    if (kt >= KNT) return;
    const int k0 = kt * 64;
#pragma unroll
    for (int r = 0; r < 2; ++r) {
      int idx = r * 512 + tid;           // 0..1023 16B-chunks
      int row = idx >> 2, c = idx & 3;
      int src = ((c * 2) ^ (row & 6)) * 8;  // 16B-contiguous (row&6 even)
      gload_lds16(A8 + (size_t)(m0 + row) * Kd + k0 + src, &As[buf][row * 64 + c * 16]);
    }
  };
  auto stageB = [&](int kt, int buf) {
    if (kt >= KNT) return;
    const int k0 = kt * 64;
    {
      int idx = tid;                     // 0..511
      int row = idx >> 2, c = idx & 3;
      int src = ((c * 2) ^ (row & 6)) * 8;
      gload_lds16(B8 + (size_t)(n0 + row) * Kd + k0 + src, &Bs[buf][row * 64 + c * 16]);
    }
  };

  // prologue: tiles 0,1,2 into bufs 0,1,2 (9 loads/thread outstanding)
  stageA(0, 0); stageB(0, 0);
  stageA(1, 1); stageB(1, 1);
  stageA(2, 2); stageB(2, 2);

  int buf = 0;
  for (int g = 0; g < KNT; ++g) {
    if (g < KNT - 2)      asm volatile("s_waitcnt vmcnt(6)" ::: "memory");  // tile g landed, g+1/g+2 fly
    else if (g == KNT - 2) asm volatile("s_waitcnt vmcnt(3)" ::: "memory");
    else                   asm volatile("s_waitcnt vmcnt(0)" ::: "memory");
    __builtin_amdgcn_sched_barrier(0);
    __builtin_amdgcn_s_barrier();
    __builtin_amdgcn_sched_barrier(0);

    long bfr[4][2];
#pragma unroll
    for (int p = 0; p < 4; ++p) {
      int row = wn * 64 + p * 16 + (lane & 15);
#pragma unroll
      for (int kh = 0; kh < 2; ++kh) {
        int slot = (kh * 4 + (lane >> 4)) ^ (row & 6);
        bfr[p][kh] = *(const long*)(&Bs[buf][row * 64 + slot * 8]);
      }
    }
    __builtin_amdgcn_s_setprio(1);
#pragma unroll
    for (int q = 0; q < 4; ++q) {
      int rowA = wm * 64 + q * 16 + (lane & 15);
      long af[2];
#pragma unroll
      for (int kh = 0; kh < 2; ++kh) {
        int slot = (kh * 4 + (lane >> 4)) ^ (rowA & 6);
        af[kh] = *(const long*)(&As[buf][rowA * 64 + slot * 8]);
      }
#pragma unroll
      for (int kh = 0; kh < 2; ++kh)
#pragma unroll
        for (int p = 0; p < 4; ++p)
          acc[q][p] = __builtin_amdgcn_mfma_f32_16x16x32_fp8_fp8(bfr[p][kh], af[kh], acc[q][p], 0, 0, 0);
    }
    __builtin_amdgcn_s_setprio(0);

    __builtin_amdgcn_sched_barrier(0);
    __builtin_amdgcn_s_barrier();
    __builtin_amdgcn_sched_barrier(0);
    // stage tile g+3 into the buffer just freed
    stageA(g + 3, buf);
    stageB(g + 3, buf);
    buf = (buf == 2) ? 0 : buf + 1;
  }

  // epilogue: bias + float4 stores (swapped layout: per lane 1 row, 4 consecutive cols)
  const int colq = (lane >> 4) * 4;
  float4 bias4[4];
#pragma unroll
  for (int p = 0; p < 4; ++p) {
    int colbase = n0 + wn * 64 + p * 16 + colq;
    bias4[p] = (colbase < Nd) ? *(const float4*)(bias + colbase) : make_float4(0.f, 0.f, 0.f, 0.f);
  }
#pragma unroll
  for (int q = 0; q < 4; ++q) {
    int row = m0 + wm * 64 + q * 16 + (lane & 15);
#pragma unroll
    for (int p = 0; p < 4; ++p) {
      int colbase = n0 + wn * 64 + p * 16 + colq;
      if (colbase < Nd) {
        f32x4 v = acc[q][p];
        float4 o = make_float4(v[0] + bias4[p].x, v[1] + bias4[p].y,
                               v[2] + bias4[p].z, v[3] + bias4[p].w);
        *(float4*)(&C[(size_t)row * ldc + colbase]) = o;
      }
    }
  }
}

extern "C" void kernel_launch(void* const* d_in, const int* in_sizes, int n_in,
                              void* d_out, int out_size, void* d_ws, size_t ws_size,
                              hipStream_t stream) {
  const float* sre = (const float*)d_in[0];
  const float* simg = (const float*)d_in[1];
  const float* cre = (const float*)d_in[2];
  const float* cim = (const float*)d_in[3];
  const float* W1 = (const float*)d_in[4];
  const float* b1 = (const float*)d_in[5];
  const float* W2 = (const float*)d_in[6];
  const float* b2 = (const float*)d_in[7];
  const float* W3 = (const float*)d_in[8];
  const float* b3 = (const float*)d_in[9];
  const float* W4 = (const float*)d_in[10];
  const float* b4 = (const float*)d_in[11];

  const int M = 2048, D = 512, Cc = 1000, V = 50000, K1 = 1024, H3 = 768;
  const int Npad2 = 392 * 128;  // 50176

  char* ws = (char*)d_ws;
  size_t off = 0;
  auto alloc = [&](size_t bytes) {
    char* p = ws + off;
    off = (off + bytes + 255) & ~(size_t)255;
    return p;
  };
  __hip_bfloat16* xcatb = (__hip_bfloat16*)alloc((size_t)M * K1 * 2);
  float* mag = (float*)alloc((size_t)M * D * 4);
  float* cmagT = (float*)alloc((size_t)D * Cc * 4);
  float* xn = (float*)alloc((size_t)M * 4);
  float* yn = (float*)alloc((size_t)Cc * 4);
  float* simsb = (float*)alloc((size_t)M * Cc * 4);
  __hip_bfloat16* h1b = (__hip_bfloat16*)alloc((size_t)M * 512 * 2);
  __hip_bfloat16* h2b = (__hip_bfloat16*)alloc((size_t)M * 512 * 2);
  unsigned char* h3f8 = (unsigned char*)alloc((size_t)M * H3);
  __hip_bfloat16* w1t = (__hip_bfloat16*)alloc((size_t)512 * K1 * 2);
  __hip_bfloat16* w2t = (__hip_bfloat16*)alloc((size_t)512 * 512 * 2);
  __hip_bfloat16* w3t = (__hip_bfloat16*)alloc((size_t)H3 * 512 * 2);
  unsigned char* w4f8 = (unsigned char*)alloc((size_t)Npad2 * H3);

  float* top_sims = (float*)d_out;
  float* top_idx = (float*)d_out + (size_t)M * 5;
  float* logits = (float*)d_out + (size_t)M * 5 * 2;

  // 1: weight transposes W1-3 + cmag + mag
  k_pre<<<dim3(3336), dim3(256), 0, stream>>>(W1, w1t, W2, w2t, W3, w3t,
                                              cre, cim, cmagT, yn, sre, simg, mag, xcatb, xn);
  // 2: MLP-L1 + dots + W4 transpose (dots hidden under trW4's HBM stream — r12 arrangement)
  k_l1w4<<<dim3(64 + 512 + 9408), dim3(256), 0, stream>>>(xcatb, w1t, h1b, b1, W4, w4f8,
                                                          mag, cmagT, simsb, xn, yn);
  // 3: MLP-L2 + top-k
  k_l2topk<<<dim3(64 + 512), dim3(256), 0, stream>>>(h1b, w2t, h2b, b2, simsb, top_sims, top_idx);
  // 4: MLP-L3
  k_l3<<<dim3(96), dim3(256), 0, stream>>>(h2b, w3t, h3f8, b3);
  // 5: big fp8 GEMM (r12 config + triple buffer)
  k_main<<<dim3(3136), dim3(512), 0, stream>>>(h3f8, w4f8, logits, b4);
}

// Round 18
// 385.876 us; speedup vs baseline: 2.8530x; 1.0007x over previous
//
#include <hip/hip_runtime.h>
#include <hip/hip_bf16.h>
#include <hip/hip_fp8.h>

#define CEPS 1e-8f

typedef __attribute__((ext_vector_type(8))) __bf16 bf16x8;
typedef __attribute__((ext_vector_type(4))) float f32x4;

__device__ __forceinline__ void gload_lds16(const void* g, void* l) {
  __builtin_amdgcn_global_load_lds((const __attribute__((address_space(1))) unsigned int*)g,
                                   (__attribute__((address_space(3))) unsigned int*)l, 16, 0, 0);
}

__device__ __forceinline__ float gelu_f(float v) {
  return 0.5f * v * (1.0f + erff(v * 0.70710678118654752f));
}

__device__ __forceinline__ unsigned char f32_to_e4m3(float v) {
  __hip_fp8_e4m3 t(v);
  return (unsigned char)t.__x;
}

// pack 4 f32 -> 4 fp8 e4m3 bytes; HW v_cvt_pk_fp8_f32 when available (RNE, OCP on gfx950)
__device__ __forceinline__ unsigned int pack4_e4m3(float a, float b, float c, float d) {
#if __has_builtin(__builtin_amdgcn_cvt_pk_fp8_f32)
  int v = __builtin_amdgcn_cvt_pk_fp8_f32(a, b, 0, false);   // bytes 0-1
  v = __builtin_amdgcn_cvt_pk_fp8_f32(c, d, v, true);        // bytes 2-3
  return (unsigned int)v;
#else
  return (unsigned int)f32_to_e4m3(a) | ((unsigned int)f32_to_e4m3(b) << 8) |
         ((unsigned int)f32_to_e4m3(c) << 16) | ((unsigned int)f32_to_e4m3(d) << 24);
#endif
}

// ================= device bodies =================

// ---- magnitude + concat(bf16) + row norm ----
__device__ __forceinline__ void dev_mag(double* red, const float* __restrict__ re,
                                        const float* __restrict__ im, float* __restrict__ mag,
                                        __hip_bfloat16* __restrict__ xcat, float* __restrict__ xn,
                                        int row) {
  const float* r = re + (size_t)row * 512;
  const float* q = im + (size_t)row * 512;
  double ss = 0.0;
  for (int d = threadIdx.x; d < 512; d += 256) {
    float a = r[d], b = q[d];
    float s = __fadd_rn(__fmul_rn(a, a), __fmul_rn(b, b));  // match np rounding
    float m = __fsqrt_rn(s);
    mag[(size_t)row * 512 + d] = m;
    xcat[(size_t)row * 1024 + d] = __float2bfloat16(a);
    xcat[(size_t)row * 1024 + 512 + d] = __float2bfloat16(b);
    ss += (double)m * (double)m;
  }
  for (int off = 32; off; off >>= 1) ss += __shfl_xor(ss, off);
  int lane = threadIdx.x & 63, wave = threadIdx.x >> 6;
  if (lane == 0) red[wave] = ss;
  __syncthreads();
  if (threadIdx.x == 0) {
    double tot = red[0] + red[1] + red[2] + red[3];
    float n = (float)sqrt(tot);
    xn[row] = fmaxf(n, CEPS);
  }
}

// ---- concept magnitude (transposed) + norms ----
__device__ __forceinline__ void dev_cmag(double* red, const float* __restrict__ cre,
                                         const float* __restrict__ cim, float* __restrict__ cmagT,
                                         float* __restrict__ yn, int c) {
  const float* r = cre + (size_t)c * 512;
  const float* q = cim + (size_t)c * 512;
  double ss = 0.0;
  for (int d = threadIdx.x; d < 512; d += 256) {
    float a = r[d], b = q[d];
    float s = __fadd_rn(__fmul_rn(a, a), __fmul_rn(b, b));
    float m = __fsqrt_rn(s);
    cmagT[(size_t)d * 1000 + c] = m;
    ss += (double)m * (double)m;
  }
  for (int off = 32; off; off >>= 1) ss += __shfl_xor(ss, off);
  int lane = threadIdx.x & 63, wave = threadIdx.x >> 6;
  if (lane == 0) red[wave] = ss;
  __syncthreads();
  if (threadIdx.x == 0) {
    double tot = red[0] + red[1] + red[2] + red[3];
    float n = (float)sqrt(tot);
    yn[c] = fmaxf(n, CEPS);
  }
}

// ---- transpose: W[K,N] f32 -> Wt[n][k] (OUTT 0=bf16, 1=fp8; zero-pad n>=N) ----
template <int OUTT>
__device__ __forceinline__ void dev_tr(float (*t32)[65], const float* __restrict__ W,
                                       void* __restrict__ Wt, int K, int N, int bx, int by) {
  int n0 = bx * 64, k0 = by * 64;
  int tid = threadIdx.x;
  {
    int nc = tid & 15, kr4 = tid >> 4;
#pragma unroll
    for (int p = 0; p < 4; ++p) {
      int kr = p * 16 + kr4;
      int n = n0 + nc * 4;
      float4 v = make_float4(0.f, 0.f, 0.f, 0.f);
      if (n < N) v = *(const float4*)(W + (size_t)(k0 + kr) * N + n);
      t32[kr][nc * 4 + 0] = v.x; t32[kr][nc * 4 + 1] = v.y;
      t32[kr][nc * 4 + 2] = v.z; t32[kr][nc * 4 + 3] = v.w;
    }
  }
  __syncthreads();
  {
    int kc = tid & 15, nr4 = tid >> 4;
#pragma unroll
    for (int p = 0; p < 4; ++p) {
      int nr = p * 16 + nr4;
      if (OUTT == 0) {
        ushort4 o;
        __hip_bfloat16 h0 = __float2bfloat16(t32[kc * 4 + 0][nr]);
        __hip_bfloat16 h1 = __float2bfloat16(t32[kc * 4 + 1][nr]);
        __hip_bfloat16 h2 = __float2bfloat16(t32[kc * 4 + 2][nr]);
        __hip_bfloat16 h3 = __float2bfloat16(t32[kc * 4 + 3][nr]);
        o.x = *(unsigned short*)&h0; o.y = *(unsigned short*)&h1;
        o.z = *(unsigned short*)&h2; o.w = *(unsigned short*)&h3;
        *(ushort4*)((unsigned short*)Wt + (size_t)(n0 + nr) * K + k0 + kc * 4) = o;
      } else {
        unsigned int o = pack4_e4m3(t32[kc * 4 + 0][nr], t32[kc * 4 + 1][nr],
                                    t32[kc * 4 + 2][nr], t32[kc * 4 + 3][nr]);
        *(unsigned int*)((unsigned char*)Wt + (size_t)(n0 + nr) * K + k0 + kc * 4) = o;
      }
    }
  }
}

// ---- 128x128 bf16 MFMA GEMM with gelu epilogue (MLP layers) ----
template <int OUTT>
__device__ __forceinline__ void dev_mlp(short* Al, short* Bl, const __hip_bfloat16* __restrict__ A,
                                        const __hip_bfloat16* __restrict__ Bt, void* __restrict__ C,
                                        int M, int N, int K, int ldc, const float* __restrict__ bias,
                                        int bx, int by) {
  const int tid = threadIdx.x, lane = tid & 63, wave = tid >> 6;
  const int m0 = by * 128, n0 = bx * 128;
  const int wr = wave >> 1, wc = wave & 1;
  f32x4 acc[4][4];
  f32x4 zero4 = {0.f, 0.f, 0.f, 0.f};
#pragma unroll
  for (int i = 0; i < 4; ++i)
#pragma unroll
    for (int j = 0; j < 4; ++j) acc[i][j] = zero4;

  const short* Ag = (const short*)A;
  const short* Bg = (const short*)Bt;
  for (int k0 = 0; k0 < K; k0 += 32) {
#pragma unroll
    for (int s = 0; s < 2; ++s) {
      int seg = wave + s * 4;
      int elem = seg * 512 + lane * 8;
      int row = elem >> 5, kk = elem & 31;
      gload_lds16(Ag + (size_t)(m0 + row) * K + k0 + kk, Al + elem);
      gload_lds16(Bg + (size_t)(n0 + row) * K + k0 + kk, Bl + elem);
    }
    __syncthreads();
    bf16x8 af[4], bfr[4];
    const int fr = lane & 15, fk = (lane >> 4) << 3;
#pragma unroll
    for (int i = 0; i < 4; ++i)
      af[i] = *(const bf16x8*)(Al + (wr * 64 + i * 16 + fr) * 32 + fk);
#pragma unroll
    for (int j = 0; j < 4; ++j)
      bfr[j] = *(const bf16x8*)(Bl + (wc * 64 + j * 16 + fr) * 32 + fk);
#pragma unroll
    for (int i = 0; i < 4; ++i)
#pragma unroll
      for (int j = 0; j < 4; ++j)
        acc[i][j] = __builtin_amdgcn_mfma_f32_16x16x32_bf16(af[i], bfr[j], acc[i][j], 0, 0, 0);
    __syncthreads();
  }
  const int fr = lane & 15, fq = lane >> 4;
#pragma unroll
  for (int j = 0; j < 4; ++j) {
    int col = n0 + wc * 64 + j * 16 + fr;
    if (col >= N) continue;
    float bv = bias[col];
#pragma unroll
    for (int i = 0; i < 4; ++i) {
      int rbase = m0 + wr * 64 + i * 16 + fq * 4;
#pragma unroll
      for (int r = 0; r < 4; ++r) {
        float v = gelu_f(acc[i][j][r] + bv);
        if (OUTT == 0)
          ((__hip_bfloat16*)C)[(size_t)(rbase + r) * ldc + col] = __float2bfloat16(v);
        else
          ((unsigned char*)C)[(size_t)(rbase + r) * ldc + col] = f32_to_e4m3(v);
      }
    }
  }
}

// ---- dots GEMM, f64 acc; LDS padded [16][65] (conflict-free); FMA order = rounds 7-17 ----
__device__ __forceinline__ void dev_dots(double (*As)[65], double (*Bs)[65],
                                         const float* __restrict__ A, const float* __restrict__ Bm,
                                         float* __restrict__ Cm, int M, int N, int K, int ldc,
                                         const float* __restrict__ xn, const float* __restrict__ yn,
                                         int nb, int mb) {
  const int tid = threadIdx.x;
  const int m0 = mb * 64, n0 = nb * 64;
  const int tx = tid & 15, ty4 = tid >> 4;
  const int ar = tid >> 2, ak = (tid & 3) << 2;
  const int bk = tid >> 4, bn = (tid & 15) << 2;
  double acc[4][4] = {};
  for (int k0 = 0; k0 < K; k0 += 16) {
    float4 a4 = *(const float4*)(A + (size_t)(m0 + ar) * K + k0 + ak);
    As[ak + 0][ar] = (double)a4.x; As[ak + 1][ar] = (double)a4.y;
    As[ak + 2][ar] = (double)a4.z; As[ak + 3][ar] = (double)a4.w;
    float4 b4 = make_float4(0.f, 0.f, 0.f, 0.f);
    if (n0 + bn < N) b4 = *(const float4*)(Bm + (size_t)(k0 + bk) * N + n0 + bn);
    Bs[bk][bn + 0] = (double)b4.x; Bs[bk][bn + 1] = (double)b4.y;
    Bs[bk][bn + 2] = (double)b4.z; Bs[bk][bn + 3] = (double)b4.w;
    __syncthreads();
#pragma unroll
    for (int kk = 0; kk < 16; ++kk) {
      double av[4], bv[4];
#pragma unroll
      for (int i = 0; i < 4; ++i) av[i] = As[kk][ty4 + i * 16];
#pragma unroll
      for (int j = 0; j < 4; ++j) bv[j] = Bs[kk][tx + j * 16];
#pragma unroll
      for (int i = 0; i < 4; ++i)
#pragma unroll
        for (int j = 0; j < 4; ++j)
          acc[i][j] = fma(av[i], bv[j], acc[i][j]);
    }
    __syncthreads();
  }
#pragma unroll
  for (int i = 0; i < 4; ++i) {
    int row = m0 + ty4 + i * 16;
#pragma unroll
    for (int j = 0; j < 4; ++j) {
      int col = n0 + tx + j * 16;
      if (col >= N) continue;
      double d = acc[i][j] / ((double)xn[row] * (double)yn[col]);
      Cm[(size_t)row * ldc + col] = (float)d;
    }
  }
}

// ---- top-5 per row (one wave per row; 4 rows per block) ----
__device__ __forceinline__ void dev_topk(const float* __restrict__ sims,
                                         float* __restrict__ top_sims, float* __restrict__ top_idx,
                                         int rowblock) {
  int lane = threadIdx.x & 63, wave = threadIdx.x >> 6;
  int row = rowblock * 4 + wave;
  const float* s = sims + (size_t)row * 1000;
  float v[16];
  int idx[16];
#pragma unroll
  for (int t = 0; t < 16; ++t) {
    int c = lane + t * 64;
    if (c < 1000) { v[t] = s[c]; idx[t] = c; }
    else { v[t] = -1e30f; idx[t] = 1 << 20; }
  }
  for (int j = 0; j < 5; ++j) {
    float bv = -1e30f; int bi = 1 << 20;
#pragma unroll
    for (int t = 0; t < 16; ++t) {
      if (v[t] > bv || (v[t] == bv && idx[t] < bi)) { bv = v[t]; bi = idx[t]; }
    }
    float rv = bv; int ri = bi;
#pragma unroll
    for (int off = 32; off; off >>= 1) {
      float ov = __shfl_xor(rv, off);
      int oi = __shfl_xor(ri, off);
      if (ov > rv || (ov == rv && oi < ri)) { rv = ov; ri = oi; }
    }
    if (lane == 0) {
      top_sims[(size_t)row * 5 + j] = rv;
      top_idx[(size_t)row * 5 + j] = (float)ri;
    }
#pragma unroll
    for (int t = 0; t < 16; ++t)
      if (idx[t] == ri) v[t] = -1e30f;
  }
}

// ================= fused launches (r17 structure — best measured 386.1us) =================

// launch 1: trW1(128) | trW2(64) | trW3(96) | cmag(1000) | mag(2048)  = 3336 blocks
__global__ __launch_bounds__(256) void k_pre(const float* W1, __hip_bfloat16* w1t,
                                             const float* W2, __hip_bfloat16* w2t,
                                             const float* W3, __hip_bfloat16* w3t,
                                             const float* cre, const float* cim, float* cmagT, float* yn,
                                             const float* sre, const float* simg, float* mag,
                                             __hip_bfloat16* xcat, float* xn) {
  __shared__ float t32[64][65];
  __shared__ double red[4];
  int bid = blockIdx.x;
  if (bid < 128) {
    dev_tr<0>(t32, W1, (void*)w1t, 1024, 512, bid & 7, bid >> 3);
  } else if (bid < 192) {
    int t = bid - 128;
    dev_tr<0>(t32, W2, (void*)w2t, 512, 512, t & 7, t >> 3);
  } else if (bid < 288) {
    int t = bid - 192;
    dev_tr<0>(t32, W3, (void*)w3t, 512, 768, t % 12, t / 12);
  } else if (bid < 1288) {
    dev_cmag(red, cre, cim, cmagT, yn, bid - 288);
  } else {
    dev_mag(red, sre, simg, mag, xcat, xn, bid - 1288);
  }
}

// launch 2: MLP-L1 (64) | dots (512, hidden under trW4's HBM stream) | trW4 fp8 (9408)
union L1W4Smem {
  struct { short Al[128 * 32]; short Bl[128 * 32]; } m;
  float t32[64][65];
  struct { double As[16][65]; double Bs[16][65]; } d;
};
__global__ __launch_bounds__(256) void k_l1w4(const __hip_bfloat16* xcat, const __hip_bfloat16* w1t,
                                              __hip_bfloat16* h1b, const float* b1,
                                              const float* W4, unsigned char* w4f8,
                                              const float* mag, const float* cmagT, float* simsb,
                                              const float* xn, const float* yn) {
  __shared__ L1W4Smem sm;
  int bid = blockIdx.x;
  if (bid < 64) {
    dev_mlp<0>(sm.m.Al, sm.m.Bl, xcat, w1t, (void*)h1b, 2048, 512, 1024, 512, b1, bid & 3, bid >> 2);
  } else if (bid < 576) {
    int id = bid - 64;  // 0..511
    dev_dots(sm.d.As, sm.d.Bs, mag, cmagT, simsb, 2048, 1000, 512, 1000, xn, yn,
             id & 15, id >> 4);
  } else {
    int t = bid - 576;
    dev_tr<1>(sm.t32, W4, (void*)w4f8, 768, 50000, t % 784, t / 784);
  }
}

// launch 3: MLP-L2 (64, bf16 out) | topk (512)
__global__ __launch_bounds__(256) void k_l2topk(const __hip_bfloat16* h1b, const __hip_bfloat16* w2t,
                                                __hip_bfloat16* h2b, const float* b2,
                                                const float* simsb, float* top_sims, float* top_idx) {
  __shared__ short Al[128 * 32];
  __shared__ short Bl[128 * 32];
  int bid = blockIdx.x;
  if (bid < 64) {
    dev_mlp<0>(Al, Bl, h1b, w2t, (void*)h2b, 2048, 512, 512, 512, b2, bid & 3, bid >> 2);
  } else {
    dev_topk(simsb, top_sims, top_idx, bid - 64);
  }
}

// launch 4: MLP-L3 (fp8 out)
__global__ __launch_bounds__(256) void k_l3(const __hip_bfloat16* h2b, const __hip_bfloat16* w3t,
                                            unsigned char* h3f8, const float* b3) {
  __shared__ short Al[128 * 32];
  __shared__ short Bl[128 * 32];
  dev_mlp<1>(Al, Bl, h2b, w3t, (void*)h3f8, 2048, 768, 512, 768, b3, blockIdx.x % 6, blockIdx.x / 6);
}

// launch 5: final-layer fp8 GEMM — r17 kernel (triple-buffered LDS, best measured).
__global__ __launch_bounds__(512, 4) void k_main(const unsigned char* __restrict__ A8,
                                                 const unsigned char* __restrict__ B8,
                                                 float* __restrict__ C, const float* __restrict__ bias) {
  const int KNT = 12;
  const int Kd = 768, Nd = 50000, ldc = 50000;
  __shared__ unsigned char As[3][16384];  // 3 x 256 rows x 64 B
  __shared__ unsigned char Bs[3][8192];   // 3 x 128 rows x 64 B
  const int tid = threadIdx.x, lane = tid & 63, wave = tid >> 6;
  const int wm = wave & 3, wn = wave >> 2;  // 4M x 2N waves, per-wave 64x64

  const int xcd = blockIdx.x & 7, j = blockIdx.x >> 3;
  const int mt = j & 7;
  const int ntile = xcd + 8 * (j >> 3);
  const int m0 = mt * 256, n0 = ntile * 128;

  f32x4 acc[4][4];
  f32x4 z4 = {0.f, 0.f, 0.f, 0.f};
#pragma unroll
  for (int q = 0; q < 4; ++q)
#pragma unroll
    for (int p = 0; p < 4; ++p) acc[q][p] = z4;

  auto stageA = [&](int kt, int buf) {
    if (kt >= KNT) return;
    const int k0 = kt * 64;
#pragma unroll
    for (int r = 0; r < 2; ++r) {
      int idx = r * 512 + tid;           // 0..1023 16B-chunks
      int row = idx >> 2, c = idx & 3;
      int src = ((c * 2) ^ (row & 6)) * 8;  // 16B-contiguous (row&6 even)
      gload_lds16(A8 + (size_t)(m0 + row) * Kd + k0 + src, &As[buf][row * 64 + c * 16]);
    }
  };
  auto stageB = [&](int kt, int buf) {
    if (kt >= KNT) return;
    const int k0 = kt * 64;
    {
      int idx = tid;                     // 0..511
      int row = idx >> 2, c = idx & 3;
      int src = ((c * 2) ^ (row & 6)) * 8;
      gload_lds16(B8 + (size_t)(n0 + row) * Kd + k0 + src, &Bs[buf][row * 64 + c * 16]);
    }
  };

  // prologue: tiles 0,1,2 into bufs 0,1,2 (9 loads/thread outstanding)
  stageA(0, 0); stageB(0, 0);
  stageA(1, 1); stageB(1, 1);
  stageA(2, 2); stageB(2, 2);

  int buf = 0;
  for (int g = 0; g < KNT; ++g) {
    if (g < KNT - 2)      asm volatile("s_waitcnt vmcnt(6)" ::: "memory");  // tile g landed, g+1/g+2 fly
    else if (g == KNT - 2) asm volatile("s_waitcnt vmcnt(3)" ::: "memory");
    else                   asm volatile("s_waitcnt vmcnt(0)" ::: "memory");
    __builtin_amdgcn_sched_barrier(0);
    __builtin_amdgcn_s_barrier();
    __builtin_amdgcn_sched_barrier(0);

    long bfr[4][2];
#pragma unroll
    for (int p = 0; p < 4; ++p) {
      int row = wn * 64 + p * 16 + (lane & 15);
#pragma unroll
      for (int kh = 0; kh < 2; ++kh) {
        int slot = (kh * 4 + (lane >> 4)) ^ (row & 6);
        bfr[p][kh] = *(const long*)(&Bs[buf][row * 64 + slot * 8]);
      }
    }
    __builtin_amdgcn_s_setprio(1);
#pragma unroll
    for (int q = 0; q < 4; ++q) {
      int rowA = wm * 64 + q * 16 + (lane & 15);
      long af[2];
#pragma unroll
      for (int kh = 0; kh < 2; ++kh) {
        int slot = (kh * 4 + (lane >> 4)) ^ (rowA & 6);
        af[kh] = *(const long*)(&As[buf][rowA * 64 + slot * 8]);
      }
#pragma unroll
      for (int kh = 0; kh < 2; ++kh)
#pragma unroll
        for (int p = 0; p < 4; ++p)
          acc[q][p] = __builtin_amdgcn_mfma_f32_16x16x32_fp8_fp8(bfr[p][kh], af[kh], acc[q][p], 0, 0, 0);
    }
    __builtin_amdgcn_s_setprio(0);

    __builtin_amdgcn_sched_barrier(0);
    __builtin_amdgcn_s_barrier();
    __builtin_amdgcn_sched_barrier(0);
    // stage tile g+3 into the buffer just freed
    stageA(g + 3, buf);
    stageB(g + 3, buf);
    buf = (buf == 2) ? 0 : buf + 1;
  }

  // epilogue: bias + float4 stores (swapped layout: per lane 1 row, 4 consecutive cols)
  const int colq = (lane >> 4) * 4;
  float4 bias4[4];
#pragma unroll
  for (int p = 0; p < 4; ++p) {
    int colbase = n0 + wn * 64 + p * 16 + colq;
    bias4[p] = (colbase < Nd) ? *(const float4*)(bias + colbase) : make_float4(0.f, 0.f, 0.f, 0.f);
  }
#pragma unroll
  for (int q = 0; q < 4; ++q) {
    int row = m0 + wm * 64 + q * 16 + (lane & 15);
#pragma unroll
    for (int p = 0; p < 4; ++p) {
      int colbase = n0 + wn * 64 + p * 16 + colq;
      if (colbase < Nd) {
        f32x4 v = acc[q][p];
        float4 o = make_float4(v[0] + bias4[p].x, v[1] + bias4[p].y,
                               v[2] + bias4[p].z, v[3] + bias4[p].w);
        *(float4*)(&C[(size_t)row * ldc + colbase]) = o;
      }
    }
  }
}

extern "C" void kernel_launch(void* const* d_in, const int* in_sizes, int n_in,
                              void* d_out, int out_size, void* d_ws, size_t ws_size,
                              hipStream_t stream) {
  const float* sre = (const float*)d_in[0];
  const float* simg = (const float*)d_in[1];
  const float* cre = (const float*)d_in[2];
  const float* cim = (const float*)d_in[3];
  const float* W1 = (const float*)d_in[4];
  const float* b1 = (const float*)d_in[5];
  const float* W2 = (const float*)d_in[6];
  const float* b2 = (const float*)d_in[7];
  const float* W3 = (const float*)d_in[8];
  const float* b3 = (const float*)d_in[9];
  const float* W4 = (const float*)d_in[10];
  const float* b4 = (const float*)d_in[11];

  const int M = 2048, D = 512, Cc = 1000, V = 50000, K1 = 1024, H3 = 768;
  const int Npad2 = 392 * 128;  // 50176

  char* ws = (char*)d_ws;
  size_t off = 0;
  auto alloc = [&](size_t bytes) {
    char* p = ws + off;
    off = (off + bytes + 255) & ~(size_t)255;
    return p;
  };
  __hip_bfloat16* xcatb = (__hip_bfloat16*)alloc((size_t)M * K1 * 2);
  float* mag = (float*)alloc((size_t)M * D * 4);
  float* cmagT = (float*)alloc((size_t)D * Cc * 4);
  float* xn = (float*)alloc((size_t)M * 4);
  float* yn = (float*)alloc((size_t)Cc * 4);
  float* simsb = (float*)alloc((size_t)M * Cc * 4);
  __hip_bfloat16* h1b = (__hip_bfloat16*)alloc((size_t)M * 512 * 2);
  __hip_bfloat16* h2b = (__hip_bfloat16*)alloc((size_t)M * 512 * 2);
  unsigned char* h3f8 = (unsigned char*)alloc((size_t)M * H3);
  __hip_bfloat16* w1t = (__hip_bfloat16*)alloc((size_t)512 * K1 * 2);
  __hip_bfloat16* w2t = (__hip_bfloat16*)alloc((size_t)512 * 512 * 2);
  __hip_bfloat16* w3t = (__hip_bfloat16*)alloc((size_t)H3 * 512 * 2);
  unsigned char* w4f8 = (unsigned char*)alloc((size_t)Npad2 * H3);

  float* top_sims = (float*)d_out;
  float* top_idx = (float*)d_out + (size_t)M * 5;
  float* logits = (float*)d_out + (size_t)M * 5 * 2;

  // 1: weight transposes W1-3 + cmag + mag
  k_pre<<<dim3(3336), dim3(256), 0, stream>>>(W1, w1t, W2, w2t, W3, w3t,
                                              cre, cim, cmagT, yn, sre, simg, mag, xcatb, xn);
  // 2: MLP-L1 + dots + W4 transpose (dots hidden under trW4's HBM stream)
  k_l1w4<<<dim3(64 + 512 + 9408), dim3(256), 0, stream>>>(xcatb, w1t, h1b, b1, W4, w4f8,
                                                          mag, cmagT, simsb, xn, yn);
  // 3: MLP-L2 + top-k
  k_l2topk<<<dim3(64 + 512), dim3(256), 0, stream>>>(h1b, w2t, h2b, b2, simsb, top_sims, top_idx);
  // 4: MLP-L3
  k_l3<<<dim3(96), dim3(256), 0, stream>>>(h2b, w3t, h3f8, b3);
  // 5: big fp8 GEMM (r17 config)
  k_main<<<dim3(3136), dim3(512), 0, stream>>>(h3f8, w4f8, logits, b4);
}

// Round 19
// 383.662 us; speedup vs baseline: 2.8694x; 1.0058x over previous
//
#include <hip/hip_runtime.h>
#include <hip/hip_bf16.h>
#include <hip/hip_fp8.h>

#define CEPS 1e-8f

typedef __attribute__((ext_vector_type(8))) __bf16 bf16x8;
typedef __attribute__((ext_vector_type(4))) float f32x4;

__device__ __forceinline__ void gload_lds16(const void* g, void* l) {
  __builtin_amdgcn_global_load_lds((const __attribute__((address_space(1))) unsigned int*)g,
                                   (__attribute__((address_space(3))) unsigned int*)l, 16, 0, 0);
}

__device__ __forceinline__ float gelu_f(float v) {
  return 0.5f * v * (1.0f + erff(v * 0.70710678118654752f));
}

__device__ __forceinline__ unsigned char f32_to_e4m3(float v) {
  __hip_fp8_e4m3 t(v);
  return (unsigned char)t.__x;
}

// pack 4 f32 -> 4 fp8 e4m3 bytes; HW v_cvt_pk_fp8_f32 when available (RNE, OCP on gfx950)
__device__ __forceinline__ unsigned int pack4_e4m3(float a, float b, float c, float d) {
#if __has_builtin(__builtin_amdgcn_cvt_pk_fp8_f32)
  int v = __builtin_amdgcn_cvt_pk_fp8_f32(a, b, 0, false);   // bytes 0-1
  v = __builtin_amdgcn_cvt_pk_fp8_f32(c, d, v, true);        // bytes 2-3
  return (unsigned int)v;
#else
  return (unsigned int)f32_to_e4m3(a) | ((unsigned int)f32_to_e4m3(b) << 8) |
         ((unsigned int)f32_to_e4m3(c) << 16) | ((unsigned int)f32_to_e4m3(d) << 24);
#endif
}

// ================= device bodies =================

// ---- magnitude + concat(bf16) + row norm ----
__device__ __forceinline__ void dev_mag(double* red, const float* __restrict__ re,
                                        const float* __restrict__ im, float* __restrict__ mag,
                                        __hip_bfloat16* __restrict__ xcat, float* __restrict__ xn,
                                        int row) {
  const float* r = re + (size_t)row * 512;
  const float* q = im + (size_t)row * 512;
  double ss = 0.0;
  for (int d = threadIdx.x; d < 512; d += 256) {
    float a = r[d], b = q[d];
    float s = __fadd_rn(__fmul_rn(a, a), __fmul_rn(b, b));  // match np rounding
    float m = __fsqrt_rn(s);
    mag[(size_t)row * 512 + d] = m;
    xcat[(size_t)row * 1024 + d] = __float2bfloat16(a);
    xcat[(size_t)row * 1024 + 512 + d] = __float2bfloat16(b);
    ss += (double)m * (double)m;
  }
  for (int off = 32; off; off >>= 1) ss += __shfl_xor(ss, off);
  int lane = threadIdx.x & 63, wave = threadIdx.x >> 6;
  if (lane == 0) red[wave] = ss;
  __syncthreads();
  if (threadIdx.x == 0) {
    double tot = red[0] + red[1] + red[2] + red[3];
    float n = (float)sqrt(tot);
    xn[row] = fmaxf(n, CEPS);
  }
}

// ---- concept magnitude (transposed) + norms ----
__device__ __forceinline__ void dev_cmag(double* red, const float* __restrict__ cre,
                                         const float* __restrict__ cim, float* __restrict__ cmagT,
                                         float* __restrict__ yn, int c) {
  const float* r = cre + (size_t)c * 512;
  const float* q = cim + (size_t)c * 512;
  double ss = 0.0;
  for (int d = threadIdx.x; d < 512; d += 256) {
    float a = r[d], b = q[d];
    float s = __fadd_rn(__fmul_rn(a, a), __fmul_rn(b, b));
    float m = __fsqrt_rn(s);
    cmagT[(size_t)d * 1000 + c] = m;
    ss += (double)m * (double)m;
  }
  for (int off = 32; off; off >>= 1) ss += __shfl_xor(ss, off);
  int lane = threadIdx.x & 63, wave = threadIdx.x >> 6;
  if (lane == 0) red[wave] = ss;
  __syncthreads();
  if (threadIdx.x == 0) {
    double tot = red[0] + red[1] + red[2] + red[3];
    float n = (float)sqrt(tot);
    yn[c] = fmaxf(n, CEPS);
  }
}

// ---- transpose: W[K,N] f32 -> Wt[n][k] (OUTT 0=bf16, 1=fp8; zero-pad n>=N) ----
template <int OUTT>
__device__ __forceinline__ void dev_tr(float (*t32)[65], const float* __restrict__ W,
                                       void* __restrict__ Wt, int K, int N, int bx, int by) {
  int n0 = bx * 64, k0 = by * 64;
  int tid = threadIdx.x;
  {
    int nc = tid & 15, kr4 = tid >> 4;
#pragma unroll
    for (int p = 0; p < 4; ++p) {
      int kr = p * 16 + kr4;
      int n = n0 + nc * 4;
      float4 v = make_float4(0.f, 0.f, 0.f, 0.f);
      if (n < N) v = *(const float4*)(W + (size_t)(k0 + kr) * N + n);
      t32[kr][nc * 4 + 0] = v.x; t32[kr][nc * 4 + 1] = v.y;
      t32[kr][nc * 4 + 2] = v.z; t32[kr][nc * 4 + 3] = v.w;
    }
  }
  __syncthreads();
  {
    int kc = tid & 15, nr4 = tid >> 4;
#pragma unroll
    for (int p = 0; p < 4; ++p) {
      int nr = p * 16 + nr4;
      if (OUTT == 0) {
        ushort4 o;
        __hip_bfloat16 h0 = __float2bfloat16(t32[kc * 4 + 0][nr]);
        __hip_bfloat16 h1 = __float2bfloat16(t32[kc * 4 + 1][nr]);
        __hip_bfloat16 h2 = __float2bfloat16(t32[kc * 4 + 2][nr]);
        __hip_bfloat16 h3 = __float2bfloat16(t32[kc * 4 + 3][nr]);
        o.x = *(unsigned short*)&h0; o.y = *(unsigned short*)&h1;
        o.z = *(unsigned short*)&h2; o.w = *(unsigned short*)&h3;
        *(ushort4*)((unsigned short*)Wt + (size_t)(n0 + nr) * K + k0 + kc * 4) = o;
      } else {
        unsigned int o = pack4_e4m3(t32[kc * 4 + 0][nr], t32[kc * 4 + 1][nr],
                                    t32[kc * 4 + 2][nr], t32[kc * 4 + 3][nr]);
        *(unsigned int*)((unsigned char*)Wt + (size_t)(n0 + nr) * K + k0 + kc * 4) = o;
      }
    }
  }
}

// ---- 128x128 bf16 MFMA GEMM with gelu epilogue (MLP layers) ----
template <int OUTT>
__device__ __forceinline__ void dev_mlp(short* Al, short* Bl, const __hip_bfloat16* __restrict__ A,
                                        const __hip_bfloat16* __restrict__ Bt, void* __restrict__ C,
                                        int M, int N, int K, int ldc, const float* __restrict__ bias,
                                        int bx, int by) {
  const int tid = threadIdx.x, lane = tid & 63, wave = tid >> 6;
  const int m0 = by * 128, n0 = bx * 128;
  const int wr = wave >> 1, wc = wave & 1;
  f32x4 acc[4][4];
  f32x4 zero4 = {0.f, 0.f, 0.f, 0.f};
#pragma unroll
  for (int i = 0; i < 4; ++i)
#pragma unroll
    for (int j = 0; j < 4; ++j) acc[i][j] = zero4;

  const short* Ag = (const short*)A;
  const short* Bg = (const short*)Bt;
  for (int k0 = 0; k0 < K; k0 += 32) {
#pragma unroll
    for (int s = 0; s < 2; ++s) {
      int seg = wave + s * 4;
      int elem = seg * 512 + lane * 8;
      int row = elem >> 5, kk = elem & 31;
      gload_lds16(Ag + (size_t)(m0 + row) * K + k0 + kk, Al + elem);
      gload_lds16(Bg + (size_t)(n0 + row) * K + k0 + kk, Bl + elem);
    }
    __syncthreads();
    bf16x8 af[4], bfr[4];
    const int fr = lane & 15, fk = (lane >> 4) << 3;
#pragma unroll
    for (int i = 0; i < 4; ++i)
      af[i] = *(const bf16x8*)(Al + (wr * 64 + i * 16 + fr) * 32 + fk);
#pragma unroll
    for (int j = 0; j < 4; ++j)
      bfr[j] = *(const bf16x8*)(Bl + (wc * 64 + j * 16 + fr) * 32 + fk);
#pragma unroll
    for (int i = 0; i < 4; ++i)
#pragma unroll
      for (int j = 0; j < 4; ++j)
        acc[i][j] = __builtin_amdgcn_mfma_f32_16x16x32_bf16(af[i], bfr[j], acc[i][j], 0, 0, 0);
    __syncthreads();
  }
  const int fr = lane & 15, fq = lane >> 4;
#pragma unroll
  for (int j = 0; j < 4; ++j) {
    int col = n0 + wc * 64 + j * 16 + fr;
    if (col >= N) continue;
    float bv = bias[col];
#pragma unroll
    for (int i = 0; i < 4; ++i) {
      int rbase = m0 + wr * 64 + i * 16 + fq * 4;
#pragma unroll
      for (int r = 0; r < 4; ++r) {
        float v = gelu_f(acc[i][j][r] + bv);
        if (OUTT == 0)
          ((__hip_bfloat16*)C)[(size_t)(rbase + r) * ldc + col] = __float2bfloat16(v);
        else
          ((unsigned char*)C)[(size_t)(rbase + r) * ldc + col] = f32_to_e4m3(v);
      }
    }
  }
}

// ---- dots GEMM, f64 acc; LDS padded [16][65] (conflict-free); FMA order = rounds 7-18 ----
__device__ __forceinline__ void dev_dots(double (*As)[65], double (*Bs)[65],
                                         const float* __restrict__ A, const float* __restrict__ Bm,
                                         float* __restrict__ Cm, int M, int N, int K, int ldc,
                                         const float* __restrict__ xn, const float* __restrict__ yn,
                                         int nb, int mb) {
  const int tid = threadIdx.x;
  const int m0 = mb * 64, n0 = nb * 64;
  const int tx = tid & 15, ty4 = tid >> 4;
  const int ar = tid >> 2, ak = (tid & 3) << 2;
  const int bk = tid >> 4, bn = (tid & 15) << 2;
  double acc[4][4] = {};
  for (int k0 = 0; k0 < K; k0 += 16) {
    float4 a4 = *(const float4*)(A + (size_t)(m0 + ar) * K + k0 + ak);
    As[ak + 0][ar] = (double)a4.x; As[ak + 1][ar] = (double)a4.y;
    As[ak + 2][ar] = (double)a4.z; As[ak + 3][ar] = (double)a4.w;
    float4 b4 = make_float4(0.f, 0.f, 0.f, 0.f);
    if (n0 + bn < N) b4 = *(const float4*)(Bm + (size_t)(k0 + bk) * N + n0 + bn);
    Bs[bk][bn + 0] = (double)b4.x; Bs[bk][bn + 1] = (double)b4.y;
    Bs[bk][bn + 2] = (double)b4.z; Bs[bk][bn + 3] = (double)b4.w;
    __syncthreads();
#pragma unroll
    for (int kk = 0; kk < 16; ++kk) {
      double av[4], bv[4];
#pragma unroll
      for (int i = 0; i < 4; ++i) av[i] = As[kk][ty4 + i * 16];
#pragma unroll
      for (int j = 0; j < 4; ++j) bv[j] = Bs[kk][tx + j * 16];
#pragma unroll
      for (int i = 0; i < 4; ++i)
#pragma unroll
        for (int j = 0; j < 4; ++j)
          acc[i][j] = fma(av[i], bv[j], acc[i][j]);
    }
    __syncthreads();
  }
#pragma unroll
  for (int i = 0; i < 4; ++i) {
    int row = m0 + ty4 + i * 16;
#pragma unroll
    for (int j = 0; j < 4; ++j) {
      int col = n0 + tx + j * 16;
      if (col >= N) continue;
      double d = acc[i][j] / ((double)xn[row] * (double)yn[col]);
      Cm[(size_t)row * ldc + col] = (float)d;
    }
  }
}

// ---- top-5 per row (one wave per row; 4 rows per block) ----
__device__ __forceinline__ void dev_topk(const float* __restrict__ sims,
                                         float* __restrict__ top_sims, float* __restrict__ top_idx,
                                         int rowblock) {
  int lane = threadIdx.x & 63, wave = threadIdx.x >> 6;
  int row = rowblock * 4 + wave;
  const float* s = sims + (size_t)row * 1000;
  float v[16];
  int idx[16];
#pragma unroll
  for (int t = 0; t < 16; ++t) {
    int c = lane + t * 64;
    if (c < 1000) { v[t] = s[c]; idx[t] = c; }
    else { v[t] = -1e30f; idx[t] = 1 << 20; }
  }
  for (int j = 0; j < 5; ++j) {
    float bv = -1e30f; int bi = 1 << 20;
#pragma unroll
    for (int t = 0; t < 16; ++t) {
      if (v[t] > bv || (v[t] == bv && idx[t] < bi)) { bv = v[t]; bi = idx[t]; }
    }
    float rv = bv; int ri = bi;
#pragma unroll
    for (int off = 32; off; off >>= 1) {
      float ov = __shfl_xor(rv, off);
      int oi = __shfl_xor(ri, off);
      if (ov > rv || (ov == rv && oi < ri)) { rv = ov; ri = oi; }
    }
    if (lane == 0) {
      top_sims[(size_t)row * 5 + j] = rv;
      top_idx[(size_t)row * 5 + j] = (float)ri;
    }
#pragma unroll
    for (int t = 0; t < 16; ++t)
      if (idx[t] == ri) v[t] = -1e30f;
  }
}

// ================= fused launches (r18 structure — best measured 385.9us) =================

// launch 1: trW1(128) | trW2(64) | trW3(96) | cmag(1000) | mag(2048)  = 3336 blocks
__global__ __launch_bounds__(256) void k_pre(const float* W1, __hip_bfloat16* w1t,
                                             const float* W2, __hip_bfloat16* w2t,
                                             const float* W3, __hip_bfloat16* w3t,
                                             const float* cre, const float* cim, float* cmagT, float* yn,
                                             const float* sre, const float* simg, float* mag,
                                             __hip_bfloat16* xcat, float* xn) {
  __shared__ float t32[64][65];
  __shared__ double red[4];
  int bid = blockIdx.x;
  if (bid < 128) {
    dev_tr<0>(t32, W1, (void*)w1t, 1024, 512, bid & 7, bid >> 3);
  } else if (bid < 192) {
    int t = bid - 128;
    dev_tr<0>(t32, W2, (void*)w2t, 512, 512, t & 7, t >> 3);
  } else if (bid < 288) {
    int t = bid - 192;
    dev_tr<0>(t32, W3, (void*)w3t, 512, 768, t % 12, t / 12);
  } else if (bid < 1288) {
    dev_cmag(red, cre, cim, cmagT, yn, bid - 288);
  } else {
    dev_mag(red, sre, simg, mag, xcat, xn, bid - 1288);
  }
}

// launch 2: MLP-L1 (64) | dots (512, hidden under trW4's HBM stream) | trW4 fp8 (9408)
union L1W4Smem {
  struct { short Al[128 * 32]; short Bl[128 * 32]; } m;
  float t32[64][65];
  struct { double As[16][65]; double Bs[16][65]; } d;
};
__global__ __launch_bounds__(256) void k_l1w4(const __hip_bfloat16* xcat, const __hip_bfloat16* w1t,
                                              __hip_bfloat16* h1b, const float* b1,
                                              const float* W4, unsigned char* w4f8,
                                              const float* mag, const float* cmagT, float* simsb,
                                              const float* xn, const float* yn) {
  __shared__ L1W4Smem sm;
  int bid = blockIdx.x;
  if (bid < 64) {
    dev_mlp<0>(sm.m.Al, sm.m.Bl, xcat, w1t, (void*)h1b, 2048, 512, 1024, 512, b1, bid & 3, bid >> 2);
  } else if (bid < 576) {
    int id = bid - 64;  // 0..511
    dev_dots(sm.d.As, sm.d.Bs, mag, cmagT, simsb, 2048, 1000, 512, 1000, xn, yn,
             id & 15, id >> 4);
  } else {
    int t = bid - 576;
    dev_tr<1>(sm.t32, W4, (void*)w4f8, 768, 50000, t % 784, t / 784);
  }
}

// launch 3: MLP-L2 (64, bf16 out) | topk (512)
__global__ __launch_bounds__(256) void k_l2topk(const __hip_bfloat16* h1b, const __hip_bfloat16* w2t,
                                                __hip_bfloat16* h2b, const float* b2,
                                                const float* simsb, float* top_sims, float* top_idx) {
  __shared__ short Al[128 * 32];
  __shared__ short Bl[128 * 32];
  int bid = blockIdx.x;
  if (bid < 64) {
    dev_mlp<0>(Al, Bl, h1b, w2t, (void*)h2b, 2048, 512, 512, 512, b2, bid & 3, bid >> 2);
  } else {
    dev_topk(simsb, top_sims, top_idx, bid - 64);
  }
}

// launch 4: MLP-L3 (fp8 out)
__global__ __launch_bounds__(256) void k_l3(const __hip_bfloat16* h2b, const __hip_bfloat16* w3t,
                                            unsigned char* h3f8, const float* b3) {
  __shared__ short Al[128 * 32];
  __shared__ short Bl[128 * 32];
  dev_mlp<1>(Al, Bl, h2b, w3t, (void*)h3f8, 2048, 768, 512, 768, b3, blockIdx.x % 6, blockIdx.x / 6);
}

// launch 5: final-layer fp8 GEMM — r17 triple-buffer kernel with ONE barrier per K-tile.
// The trailing barrier is removed: staging tile g+2 happens AFTER the leading barrier of
// iteration g, into buf((g+2)%3) = buf((g-1)%3), whose reads (tile g-1, iter g-1) are
// complete block-wide once any wave passes this barrier (program order). Laggard-safe:
// waves racing ahead block at the next leading barrier before any overwrite can occur.
// Steady-state depth unchanged (2 tiles in flight after the stage); 12 rendezvous removed.
__global__ __launch_bounds__(512, 4) void k_main(const unsigned char* __restrict__ A8,
                                                 const unsigned char* __restrict__ B8,
                                                 float* __restrict__ C, const float* __restrict__ bias) {
  const int KNT = 12;
  const int Kd = 768, Nd = 50000, ldc = 50000;
  __shared__ unsigned char As[3][16384];  // 3 x 256 rows x 64 B
  __shared__ unsigned char Bs[3][8192];   // 3 x 128 rows x 64 B
  const int tid = threadIdx.x, lane = tid & 63, wave = tid >> 6;
  const int wm = wave & 3, wn = wave >> 2;  // 4M x 2N waves, per-wave 64x64

  const int xcd = blockIdx.x & 7, j = blockIdx.x >> 3;
  const int mt = j & 7;
  const int ntile = xcd + 8 * (j >> 3);
  const int m0 = mt * 256, n0 = ntile * 128;

  f32x4 acc[4][4];
  f32x4 z4 = {0.f, 0.f, 0.f, 0.f};
#pragma unroll
  for (int q = 0; q < 4; ++q)
#pragma unroll
    for (int p = 0; p < 4; ++p) acc[q][p] = z4;

  auto stageA = [&](int kt, int buf) {
    if (kt >= KNT) return;
    const int k0 = kt * 64;
#pragma unroll
    for (int r = 0; r < 2; ++r) {
      int idx = r * 512 + tid;           // 0..1023 16B-chunks
      int row = idx >> 2, c = idx & 3;
      int src = ((c * 2) ^ (row & 6)) * 8;  // 16B-contiguous (row&6 even)
      gload_lds16(A8 + (size_t)(m0 + row) * Kd + k0 + src, &As[buf][row * 64 + c * 16]);
    }
  };
  auto stageB = [&](int kt, int buf) {
    if (kt >= KNT) return;
    const int k0 = kt * 64;
    {
      int idx = tid;                     // 0..511
      int row = idx >> 2, c = idx & 3;
      int src = ((c * 2) ^ (row & 6)) * 8;
      gload_lds16(B8 + (size_t)(n0 + row) * Kd + k0 + src, &Bs[buf][row * 64 + c * 16]);
    }
  };

  // prologue: tiles 0,1 into bufs 0,1 (6 loads/thread outstanding)
  stageA(0, 0); stageB(0, 0);
  stageA(1, 1); stageB(1, 1);

  for (int g = 0; g < KNT; ++g) {
    const int buf = g % 3;
    if (g < KNT - 1) asm volatile("s_waitcnt vmcnt(3)" ::: "memory");  // tile g landed (g+1 in flight)
    else             asm volatile("s_waitcnt vmcnt(0)" ::: "memory");
    __builtin_amdgcn_sched_barrier(0);
    __builtin_amdgcn_s_barrier();
    __builtin_amdgcn_sched_barrier(0);
    // stage tile g+2 into buf((g+2)%3) — tile g-1's buffer, reads completed before this barrier
    stageA(g + 2, (g + 2) % 3);
    stageB(g + 2, (g + 2) % 3);

    long bfr[4][2];
#pragma unroll
    for (int p = 0; p < 4; ++p) {
      int row = wn * 64 + p * 16 + (lane & 15);
#pragma unroll
      for (int kh = 0; kh < 2; ++kh) {
        int slot = (kh * 4 + (lane >> 4)) ^ (row & 6);
        bfr[p][kh] = *(const long*)(&Bs[buf][row * 64 + slot * 8]);
      }
    }
    __builtin_amdgcn_s_setprio(1);
#pragma unroll
    for (int q = 0; q < 4; ++q) {
      int rowA = wm * 64 + q * 16 + (lane & 15);
      long af[2];
#pragma unroll
      for (int kh = 0; kh < 2; ++kh) {
        int slot = (kh * 4 + (lane >> 4)) ^ (rowA & 6);
        af[kh] = *(const long*)(&As[buf][rowA * 64 + slot * 8]);
      }
#pragma unroll
      for (int kh = 0; kh < 2; ++kh)
#pragma unroll
        for (int p = 0; p < 4; ++p)
          acc[q][p] = __builtin_amdgcn_mfma_f32_16x16x32_fp8_fp8(bfr[p][kh], af[kh], acc[q][p], 0, 0, 0);
    }
    __builtin_amdgcn_s_setprio(0);
    // no trailing barrier: next iteration's leading barrier provides the rendezvous
  }

  // epilogue: bias + float4 stores (swapped layout: per lane 1 row, 4 consecutive cols)
  const int colq = (lane >> 4) * 4;
  float4 bias4[4];
#pragma unroll
  for (int p = 0; p < 4; ++p) {
    int colbase = n0 + wn * 64 + p * 16 + colq;
    bias4[p] = (colbase < Nd) ? *(const float4*)(bias + colbase) : make_float4(0.f, 0.f, 0.f, 0.f);
  }
#pragma unroll
  for (int q = 0; q < 4; ++q) {
    int row = m0 + wm * 64 + q * 16 + (lane & 15);
#pragma unroll
    for (int p = 0; p < 4; ++p) {
      int colbase = n0 + wn * 64 + p * 16 + colq;
      if (colbase < Nd) {
        f32x4 v = acc[q][p];
        float4 o = make_float4(v[0] + bias4[p].x, v[1] + bias4[p].y,
                               v[2] + bias4[p].z, v[3] + bias4[p].w);
        *(float4*)(&C[(size_t)row * ldc + colbase]) = o;
      }
    }
  }
}

extern "C" void kernel_launch(void* const* d_in, const int* in_sizes, int n_in,
                              void* d_out, int out_size, void* d_ws, size_t ws_size,
                              hipStream_t stream) {
  const float* sre = (const float*)d_in[0];
  const float* simg = (const float*)d_in[1];
  const float* cre = (const float*)d_in[2];
  const float* cim = (const float*)d_in[3];
  const float* W1 = (const float*)d_in[4];
  const float* b1 = (const float*)d_in[5];
  const float* W2 = (const float*)d_in[6];
  const float* b2 = (const float*)d_in[7];
  const float* W3 = (const float*)d_in[8];
  const float* b3 = (const float*)d_in[9];
  const float* W4 = (const float*)d_in[10];
  const float* b4 = (const float*)d_in[11];

  const int M = 2048, D = 512, Cc = 1000, V = 50000, K1 = 1024, H3 = 768;
  const int Npad2 = 392 * 128;  // 50176

  char* ws = (char*)d_ws;
  size_t off = 0;
  auto alloc = [&](size_t bytes) {
    char* p = ws + off;
    off = (off + bytes + 255) & ~(size_t)255;
    return p;
  };
  __hip_bfloat16* xcatb = (__hip_bfloat16*)alloc((size_t)M * K1 * 2);
  float* mag = (float*)alloc((size_t)M * D * 4);
  float* cmagT = (float*)alloc((size_t)D * Cc * 4);
  float* xn = (float*)alloc((size_t)M * 4);
  float* yn = (float*)alloc((size_t)Cc * 4);
  float* simsb = (float*)alloc((size_t)M * Cc * 4);
  __hip_bfloat16* h1b = (__hip_bfloat16*)alloc((size_t)M * 512 * 2);
  __hip_bfloat16* h2b = (__hip_bfloat16*)alloc((size_t)M * 512 * 2);
  unsigned char* h3f8 = (unsigned char*)alloc((size_t)M * H3);
  __hip_bfloat16* w1t = (__hip_bfloat16*)alloc((size_t)512 * K1 * 2);
  __hip_bfloat16* w2t = (__hip_bfloat16*)alloc((size_t)512 * 512 * 2);
  __hip_bfloat16* w3t = (__hip_bfloat16*)alloc((size_t)H3 * 512 * 2);
  unsigned char* w4f8 = (unsigned char*)alloc((size_t)Npad2 * H3);

  float* top_sims = (float*)d_out;
  float* top_idx = (float*)d_out + (size_t)M * 5;
  float* logits = (float*)d_out + (size_t)M * 5 * 2;

  // 1: weight transposes W1-3 + cmag + mag
  k_pre<<<dim3(3336), dim3(256), 0, stream>>>(W1, w1t, W2, w2t, W3, w3t,
                                              cre, cim, cmagT, yn, sre, simg, mag, xcatb, xn);
  // 2: MLP-L1 + dots + W4 transpose (dots hidden under trW4's HBM stream)
  k_l1w4<<<dim3(64 + 512 + 9408), dim3(256), 0, stream>>>(xcatb, w1t, h1b, b1, W4, w4f8,
                                                          mag, cmagT, simsb, xn, yn);
  // 3: MLP-L2 + top-k
  k_l2topk<<<dim3(64 + 512), dim3(256), 0, stream>>>(h1b, w2t, h2b, b2, simsb, top_sims, top_idx);
  // 4: MLP-L3
  k_l3<<<dim3(96), dim3(256), 0, stream>>>(h2b, w3t, h3f8, b3);
  // 5: big fp8 GEMM (single-barrier triple-buffer)
  k_main<<<dim3(3136), dim3(512), 0, stream>>>(h3f8, w4f8, logits, b4);
}